// Round 1
// 1107.991 us; speedup vs baseline: 1.3480x; 1.3480x over previous
//
#include <hip/hip_runtime.h>
#include <stdint.h>

// Problem constants (fixed by the reference).
#define NN 16384      // nodes
#define EE 524288     // edges
#define BB 32         // batch
#define DD 64         // input dim
#define OO 64         // output dim
#define MM 5          // num diffusion matrices
#define KK 320        // D*M  (GEMM reduction dim)
#define KP 328        // padded LDS stride for A tile

typedef __attribute__((ext_vector_type(8))) short short8;
typedef __attribute__((ext_vector_type(4))) float floatx4;

__device__ __forceinline__ float bf2f(unsigned short u) {
    return __uint_as_float(((unsigned int)u) << 16);
}
__device__ __forceinline__ unsigned short f2bf(float f) {
    unsigned int u = __float_as_uint(f);
    u += 0x7fffu + ((u >> 16) & 1u);   // round-to-nearest-even
    return (unsigned short)(u >> 16);
}
__device__ __forceinline__ unsigned int pack2(float a, float b) {
    return (unsigned int)f2bf(a) | ((unsigned int)f2bf(b) << 16);
}

// ---------------------------------------------------------------- histogram
__global__ __launch_bounds__(256) void hist_kernel(
    const float* __restrict__ adj, const int* __restrict__ rows,
    const int* __restrict__ cols,
    float* __restrict__ drow, float* __restrict__ dcol,
    int* __restrict__ cnt_row, int* __restrict__ cnt_col)
{
    int e = blockIdx.x * 256 + threadIdx.x;
    if (e < EE) {
        float a = adj[e];
        int r = rows[e], c = cols[e];
        atomicAdd(&drow[r], a);
        atomicAdd(&dcol[c], a);
        atomicAdd(&cnt_row[r], 1);
        atomicAdd(&cnt_col[c], 1);
    }
}

// ---------------------------------------------------------------- scan
// One block per array (grid=2), 1024 threads, 16 elements/thread.
__global__ __launch_bounds__(1024) void scan_kernel(
    const int* __restrict__ cnt_col, const int* __restrict__ cnt_row,
    int* __restrict__ off_col, int* __restrict__ off_row,
    int* __restrict__ cur_col, int* __restrict__ cur_row)
{
    const int* cnt = (blockIdx.x == 0) ? cnt_col : cnt_row;
    int* off = (blockIdx.x == 0) ? off_col : off_row;
    int* cur = (blockIdx.x == 0) ? cur_col : cur_row;

    __shared__ int part[1024];
    int t = threadIdx.x;
    int base = t * 16;
    int local[16];
    int s = 0;
#pragma unroll
    for (int i = 0; i < 16; i++) { local[i] = cnt[base + i]; s += local[i]; }
    part[t] = s;
    __syncthreads();
    for (int d = 1; d < 1024; d <<= 1) {
        int v = (t >= d) ? part[t - d] : 0;
        __syncthreads();
        part[t] += v;
        __syncthreads();
    }
    int run = (t == 0) ? 0 : part[t - 1];
#pragma unroll
    for (int i = 0; i < 16; i++) {
        off[base + i] = run;
        cur[base + i] = run;
        run += local[i];
    }
    if (t == 1023) off[NN] = run;
}

// ---------------------------------------------------------------- scatter
// Builds packed CSR edge arrays: edge[e] = {src, w_as_bits}
__global__ __launch_bounds__(256) void scatter_kernel(
    const float* __restrict__ adj, const int* __restrict__ rows,
    const int* __restrict__ cols,
    const float* __restrict__ drow, const float* __restrict__ dcol,
    int* __restrict__ cur_col, int* __restrict__ cur_row,
    int2* __restrict__ edge1, int2* __restrict__ edge2)
{
    int e = blockIdx.x * 256 + threadIdx.x;
    if (e < EE) {
        float a = adj[e];
        int r = rows[e], c = cols[e];
        float dr = drow[r];
        float idr = (dr > 0.f) ? (1.f / dr) : 0.f;
        float dc = dcol[c];
        float idc = (dc > 0.f) ? (1.f / dc) : 0.f;
        int p1 = atomicAdd(&cur_col[c], 1);   // support1: dst=cols, src=rows
        edge1[p1] = make_int2(r, __float_as_int(a * idr));
        int p2 = atomicAdd(&cur_row[r], 1);   // support2: dst=rows, src=cols
        edge2[p2] = make_int2(c, __float_as_int(a * idc));
    }
}

// ---------------------------------------------------------------- cast
// inputs [B,N,D] fp32 -> x0 [B,N,D] bf16
__global__ __launch_bounds__(256) void cast_kernel(
    const float* __restrict__ inp, unsigned short* __restrict__ x0)
{
    size_t i = ((size_t)blockIdx.x * 256 + threadIdx.x) * 8;
    float4 a = *(const float4*)(inp + i);
    float4 b = *(const float4*)(inp + i + 4);
    uint4 o;
    o.x = pack2(a.x, a.y);
    o.y = pack2(a.z, a.w);
    o.z = pack2(b.x, b.y);
    o.w = pack2(b.z, b.w);
    *(uint4*)(x0 + i) = o;
}

// ---------------------------------------------------------------- W prep
// Wt[o][k'] bf16 with k' = m*64 + d
__global__ __launch_bounds__(256) void wprep_kernel(
    const float* __restrict__ W, unsigned short* __restrict__ Wt)
{
    int i = blockIdx.x * 256 + threadIdx.x;
    if (i < OO * KK) {
        int o = i / KK;
        int kp = i - o * KK;
        int m = kp >> 6;
        int d = kp & 63;
        Wt[i] = f2bf(W[(d * MM + m) * OO + o]);
    }
}

// ---------------------------------------------------------------- spmm
// One block = 32 dst nodes x ONE batch slice b. Thread t: node = n0+(t>>3),
// d-group = (t&7)*8 (one uint4 = 128B segment per edge per 8-lane group).
// XCD swizzle: blkid&7 selects XCD; b = bhi*8 + xcd so all concurrent blocks
// on an XCD share one 2 MB X b-slice (captured in that XCD's 4 MB L2).
//
// Latency-bound fix (this round): the edge loop is software-pipelined in
// groups of 4 — 4 gathers in flight at once, and the NEXT group's edge
// tuples are issued before the current FMA block so the edges[]->gather
// dependent chain is hidden under compute. VGPR stays < 64 (occupancy kept).
__global__ __launch_bounds__(256) void spmm_kernel(
    const unsigned short* __restrict__ xin,
    const unsigned short* __restrict__ z,
    unsigned short* __restrict__ xout,
    const int* __restrict__ off, const int2* __restrict__ edges,
    float alpha, float beta, int has_z)
{
    unsigned int l = blockIdx.x;          // 0..16383
    int xcd  = l & 7;
    unsigned int s = l >> 3;              // 0..2047
    int bhi  = s >> 9;                    // 0..3
    int ntile = s & 511;                  // 0..511
    int b = bhi * 8 + xcd;

    int t = threadIdx.x;
    int n = ntile * 32 + (t >> 3);
    unsigned int dgb = (unsigned int)(t & 7) * 16u;   // byte offset of d-group
    int e0 = off[n], e1 = off[n + 1];
    const char* xbB = (const char*)(xin + (size_t)b * NN * DD);

    float acc[8];
#pragma unroll
    for (int j = 0; j < 8; j++) acc[j] = 0.f;

#define FMA8(V, W)                                                        \
    do {                                                                  \
        acc[0] = fmaf((W), __uint_as_float((V).x << 16), acc[0]);         \
        acc[1] = fmaf((W), __uint_as_float((V).x & 0xffff0000u), acc[1]); \
        acc[2] = fmaf((W), __uint_as_float((V).y << 16), acc[2]);         \
        acc[3] = fmaf((W), __uint_as_float((V).y & 0xffff0000u), acc[3]); \
        acc[4] = fmaf((W), __uint_as_float((V).z << 16), acc[4]);         \
        acc[5] = fmaf((W), __uint_as_float((V).z & 0xffff0000u), acc[5]); \
        acc[6] = fmaf((W), __uint_as_float((V).w << 16), acc[6]);         \
        acc[7] = fmaf((W), __uint_as_float((V).w & 0xffff0000u), acc[7]); \
    } while (0)

    int ecnt = e1 - e0;
    int nb4 = ecnt >> 2;          // number of full groups of 4 edges

    int2 ed0, ed1, ed2, ed3;
    if (nb4 > 0) {
        ed0 = edges[e0];
        ed1 = edges[e0 + 1];
        ed2 = edges[e0 + 2];
        ed3 = edges[e0 + 3];
    }
    for (int it = 0; it < nb4; ++it) {
        // 4 independent gathers in flight
        uint4 v0 = *(const uint4*)(xbB + (((unsigned int)ed0.x) << 7) + dgb);
        uint4 v1 = *(const uint4*)(xbB + (((unsigned int)ed1.x) << 7) + dgb);
        uint4 v2 = *(const uint4*)(xbB + (((unsigned int)ed2.x) << 7) + dgb);
        uint4 v3 = *(const uint4*)(xbB + (((unsigned int)ed3.x) << 7) + dgb);
        float w0 = __int_as_float(ed0.y);
        float w1 = __int_as_float(ed1.y);
        float w2 = __int_as_float(ed2.y);
        float w3 = __int_as_float(ed3.y);

        // prefetch next group's edge tuples (hides edge-load latency under FMAs)
        int2 nd0, nd1, nd2, nd3;
        int enext = e0 + (it + 1) * 4;
        if (it + 1 < nb4) {
            nd0 = edges[enext];
            nd1 = edges[enext + 1];
            nd2 = edges[enext + 2];
            nd3 = edges[enext + 3];
        }

        FMA8(v0, w0);
        FMA8(v1, w1);
        FMA8(v2, w2);
        FMA8(v3, w3);

        ed0 = nd0; ed1 = nd1; ed2 = nd2; ed3 = nd3;
    }
    // tail (<= 3 edges)
    for (int e = e0 + nb4 * 4; e < e1; ++e) {
        int2 ed = edges[e];
        float wv = __int_as_float(ed.y);
        uint4 v = *(const uint4*)(xbB + (((unsigned int)ed.x) << 7) + dgb);
        FMA8(v, wv);
    }
#undef FMA8

    size_t fo = ((size_t)b * NN + n) * DD + (dgb >> 1);
    if (has_z) {
        uint4 zv = *(const uint4*)(z + fo);
        float zf[8];
        zf[0] = __uint_as_float(zv.x << 16);
        zf[1] = __uint_as_float(zv.x & 0xffff0000u);
        zf[2] = __uint_as_float(zv.y << 16);
        zf[3] = __uint_as_float(zv.y & 0xffff0000u);
        zf[4] = __uint_as_float(zv.z << 16);
        zf[5] = __uint_as_float(zv.z & 0xffff0000u);
        zf[6] = __uint_as_float(zv.w << 16);
        zf[7] = __uint_as_float(zv.w & 0xffff0000u);
#pragma unroll
        for (int j = 0; j < 8; j++) acc[j] = alpha * acc[j] + beta * zf[j];
    }

    uint4 o;
    o.x = pack2(acc[0], acc[1]);
    o.y = pack2(acc[2], acc[3]);
    o.z = pack2(acc[4], acc[5]);
    o.w = pack2(acc[6], acc[7]);
    *(uint4*)(xout + fo) = o;
}

// ---------------------------------------------------------------- final GEMM (MFMA)
__global__ __launch_bounds__(256) void final_mfma(
    const unsigned short* __restrict__ X0, const unsigned short* __restrict__ X1,
    const unsigned short* __restrict__ X2, const unsigned short* __restrict__ X3,
    const unsigned short* __restrict__ X4,
    const unsigned short* __restrict__ Wt, const float* __restrict__ bias,
    float* __restrict__ out)
{
    __shared__ __align__(16) unsigned short A_lds[64 * KP];   // 41984 B
    int blk = blockIdx.x;
    int b = blk >> 8;
    int n0 = (blk & 255) * 64;
    int t = threadIdx.x;
    const unsigned short* Xs[MM] = {X0, X1, X2, X3, X4};

#pragma unroll
    for (int i = 0; i < 10; i++) {
        int idx = t + i * 256;             // 0..2559
        int dgv = (idx & 7) * 8;
        int row = (idx >> 3) & 63;
        int m = idx >> 9;
        uint4 v = *(const uint4*)(Xs[m] + ((size_t)b * NN + n0 + row) * DD + dgv);
        *(uint4*)&A_lds[row * KP + m * 64 + dgv] = v;
    }
    __syncthreads();

    int wave = t >> 6;
    int lane = t & 63;
    int col = lane & 15;
    int quad = lane >> 4;

    floatx4 acc[4];
#pragma unroll
    for (int ct = 0; ct < 4; ct++) acc[ct] = (floatx4){0.f, 0.f, 0.f, 0.f};

    const unsigned short* abase = &A_lds[(wave * 16 + col) * KP + quad * 8];
#pragma unroll
    for (int kt = 0; kt < 10; kt++) {
        short8 a = *(const short8*)(abase + kt * 32);
#pragma unroll
        for (int ct = 0; ct < 4; ct++) {
            short8 bf = *(const short8*)(Wt + (size_t)(ct * 16 + col) * KK + kt * 32 + quad * 8);
            acc[ct] = __builtin_amdgcn_mfma_f32_16x16x32_bf16(a, bf, acc[ct], 0, 0, 0);
        }
    }

    size_t rbase = (size_t)b * NN + n0 + wave * 16 + quad * 4;
#pragma unroll
    for (int ct = 0; ct < 4; ct++) {
        int o = ct * 16 + col;
        float bv = bias[o];
#pragma unroll
        for (int r = 0; r < 4; r++) {
            out[(rbase + r) * OO + o] = acc[ct][r] + bv;
        }
    }
}

// ---------------------------------------------------------------- launch
extern "C" void kernel_launch(void* const* d_in, const int* in_sizes, int n_in,
                              void* d_out, int out_size, void* d_ws, size_t ws_size,
                              hipStream_t stream)
{
    (void)in_sizes; (void)n_in; (void)out_size; (void)ws_size;
    const float* inputs  = (const float*)d_in[0];
    const float* adj     = (const float*)d_in[1];
    const int*   rows    = (const int*)d_in[2];
    const int*   cols    = (const int*)d_in[3];
    const float* weights = (const float*)d_in[4];
    const float* bias    = (const float*)d_in[5];
    float* out = (float*)d_out;

    char* ws = (char*)d_ws;
    size_t off = 0;
    auto alloc = [&](size_t bytes) -> char* {
        char* p = ws + off;
        off = (off + bytes + 255) & ~(size_t)255;
        return p;
    };
    float* drow    = (float*)alloc(NN * 4);
    float* dcol    = (float*)alloc(NN * 4);
    int* cnt_col   = (int*)alloc(NN * 4);
    int* cnt_row   = (int*)alloc(NN * 4);
    int* off_col   = (int*)alloc((NN + 1) * 4);
    int* off_row   = (int*)alloc((NN + 1) * 4);
    int* cur_col   = (int*)alloc(NN * 4);
    int* cur_row   = (int*)alloc(NN * 4);
    int2* edge1    = (int2*)alloc((size_t)EE * 8);
    int2* edge2    = (int2*)alloc((size_t)EE * 8);
    unsigned short* Wt = (unsigned short*)alloc((size_t)OO * KK * 2);
    unsigned short* X[MM];
    for (int m = 0; m < MM; m++) X[m] = (unsigned short*)alloc((size_t)NN * BB * DD * 2);

    // zero the atomic accumulators (drow,dcol,cnt_col,cnt_row are contiguous)
    hipMemsetAsync(drow, 0, (size_t)NN * 4 * 4, stream);

    hist_kernel<<<EE / 256, 256, 0, stream>>>(adj, rows, cols, drow, dcol,
                                              cnt_row, cnt_col);
    scan_kernel<<<2, 1024, 0, stream>>>(cnt_col, cnt_row, off_col, off_row,
                                        cur_col, cur_row);
    scatter_kernel<<<EE / 256, 256, 0, stream>>>(adj, rows, cols, drow, dcol,
                                                 cur_col, cur_row, edge1, edge2);
    cast_kernel<<<(BB * NN * DD) / (256 * 8), 256, 0, stream>>>(inputs, X[0]);
    wprep_kernel<<<(OO * KK + 255) / 256, 256, 0, stream>>>(weights, Wt);

    const int SPMM_GRID = 512 * BB;   // 512 node-tiles x 32 b, XCD-swizzled

    // xs1 = S1 x0
    spmm_kernel<<<SPMM_GRID, 256, 0, stream>>>(X[0], nullptr, X[1], off_col,
                                               edge1, 1.f, 0.f, 0);
    // xs2 = 2*S1 xs1 - x0
    spmm_kernel<<<SPMM_GRID, 256, 0, stream>>>(X[1], X[0], X[2], off_col,
                                               edge1, 2.f, -1.f, 1);
    // xs3 = S2 xs1   (x0 deliberately NOT reset between supports)
    spmm_kernel<<<SPMM_GRID, 256, 0, stream>>>(X[1], nullptr, X[3], off_row,
                                               edge2, 1.f, 0.f, 0);
    // xs4 = 2*S2 xs3 - xs1
    spmm_kernel<<<SPMM_GRID, 256, 0, stream>>>(X[3], X[1], X[4], off_row,
                                               edge2, 2.f, -1.f, 1);

    final_mfma<<<BB * (NN / 64), 256, 0, stream>>>(X[0], X[1], X[2], X[3], X[4],
                                                   Wt, bias, out);
}

// Round 2
// 1042.842 us; speedup vs baseline: 1.4322x; 1.0625x over previous
//
#include <hip/hip_runtime.h>
#include <stdint.h>

// Problem constants (fixed by the reference).
#define NN 16384      // nodes
#define EE 524288     // edges
#define BB 32         // batch
#define DD 64         // input dim
#define OO 64         // output dim
#define MM 5          // num diffusion matrices
#define KK 320        // D*M  (GEMM reduction dim)

typedef __attribute__((ext_vector_type(8))) short short8;
typedef __attribute__((ext_vector_type(4))) float floatx4;

__device__ __forceinline__ float bf2f(unsigned short u) {
    return __uint_as_float(((unsigned int)u) << 16);
}
__device__ __forceinline__ unsigned short f2bf(float f) {
    unsigned int u = __float_as_uint(f);
    u += 0x7fffu + ((u >> 16) & 1u);   // round-to-nearest-even
    return (unsigned short)(u >> 16);
}
__device__ __forceinline__ unsigned int pack2(float a, float b) {
    return (unsigned int)f2bf(a) | ((unsigned int)f2bf(b) << 16);
}

// ---------------------------------------------------------------- histogram
__global__ __launch_bounds__(256) void hist_kernel(
    const float* __restrict__ adj, const int* __restrict__ rows,
    const int* __restrict__ cols,
    float* __restrict__ drow, float* __restrict__ dcol,
    int* __restrict__ cnt_row, int* __restrict__ cnt_col)
{
    int e = blockIdx.x * 256 + threadIdx.x;
    if (e < EE) {
        float a = adj[e];
        int r = rows[e], c = cols[e];
        atomicAdd(&drow[r], a);
        atomicAdd(&dcol[c], a);
        atomicAdd(&cnt_row[r], 1);
        atomicAdd(&cnt_col[c], 1);
    }
}

// ---------------------------------------------------------------- scan
// One block per array (grid=2), 1024 threads, 16 elements/thread.
__global__ __launch_bounds__(1024) void scan_kernel(
    const int* __restrict__ cnt_col, const int* __restrict__ cnt_row,
    int* __restrict__ off_col, int* __restrict__ off_row,
    int* __restrict__ cur_col, int* __restrict__ cur_row)
{
    const int* cnt = (blockIdx.x == 0) ? cnt_col : cnt_row;
    int* off = (blockIdx.x == 0) ? off_col : off_row;
    int* cur = (blockIdx.x == 0) ? cur_col : cur_row;

    __shared__ int part[1024];
    int t = threadIdx.x;
    int base = t * 16;
    int local[16];
    int s = 0;
#pragma unroll
    for (int i = 0; i < 16; i++) { local[i] = cnt[base + i]; s += local[i]; }
    part[t] = s;
    __syncthreads();
    for (int d = 1; d < 1024; d <<= 1) {
        int v = (t >= d) ? part[t - d] : 0;
        __syncthreads();
        part[t] += v;
        __syncthreads();
    }
    int run = (t == 0) ? 0 : part[t - 1];
#pragma unroll
    for (int i = 0; i < 16; i++) {
        off[base + i] = run;
        cur[base + i] = run;
        run += local[i];
    }
    if (t == 1023) off[NN] = run;
}

// ---------------------------------------------------------------- scatter
// Builds packed CSR edge arrays: edge[e] = {src, w_as_bits}
__global__ __launch_bounds__(256) void scatter_kernel(
    const float* __restrict__ adj, const int* __restrict__ rows,
    const int* __restrict__ cols,
    const float* __restrict__ drow, const float* __restrict__ dcol,
    int* __restrict__ cur_col, int* __restrict__ cur_row,
    int2* __restrict__ edge1, int2* __restrict__ edge2)
{
    int e = blockIdx.x * 256 + threadIdx.x;
    if (e < EE) {
        float a = adj[e];
        int r = rows[e], c = cols[e];
        float dr = drow[r];
        float idr = (dr > 0.f) ? (1.f / dr) : 0.f;
        float dc = dcol[c];
        float idc = (dc > 0.f) ? (1.f / dc) : 0.f;
        int p1 = atomicAdd(&cur_col[c], 1);   // support1: dst=cols, src=rows
        edge1[p1] = make_int2(r, __float_as_int(a * idr));
        int p2 = atomicAdd(&cur_row[r], 1);   // support2: dst=rows, src=cols
        edge2[p2] = make_int2(c, __float_as_int(a * idc));
    }
}

// ---------------------------------------------------------------- cast
// inputs [B,N,D] fp32 -> x0 [B,N,D] bf16
__global__ __launch_bounds__(256) void cast_kernel(
    const float* __restrict__ inp, unsigned short* __restrict__ x0)
{
    size_t i = ((size_t)blockIdx.x * 256 + threadIdx.x) * 8;
    float4 a = *(const float4*)(inp + i);
    float4 b = *(const float4*)(inp + i + 4);
    uint4 o;
    o.x = pack2(a.x, a.y);
    o.y = pack2(a.z, a.w);
    o.z = pack2(b.x, b.y);
    o.w = pack2(b.z, b.w);
    *(uint4*)(x0 + i) = o;
}

// ---------------------------------------------------------------- W prep
// Wt[o][k'] bf16 with k' = m*64 + d
__global__ __launch_bounds__(256) void wprep_kernel(
    const float* __restrict__ W, unsigned short* __restrict__ Wt)
{
    int i = blockIdx.x * 256 + threadIdx.x;
    if (i < OO * KK) {
        int o = i / KK;
        int kp = i - o * KK;
        int m = kp >> 6;
        int d = kp & 63;
        Wt[i] = f2bf(W[(d * MM + m) * OO + o]);
    }
}

// ---------------------------------------------------------------- spmm
// One block = 32 dst nodes x ONE batch slice b. Thread t: node = n0+(t>>3),
// d-group = (t&7)*8 (one uint4 = 128B segment per edge per 8-lane group).
// XCD swizzle: blkid&7 selects XCD; b = bhi*8 + xcd so all concurrent blocks
// on an XCD share one 2 MB X b-slice (captured in that XCD's 4 MB L2).
// Edge loop software-pipelined in groups of 4 (4 gathers in flight; next
// group's edge tuples prefetched under the FMA block).
__global__ __launch_bounds__(256) void spmm_kernel(
    const unsigned short* __restrict__ xin,
    const unsigned short* __restrict__ z,
    unsigned short* __restrict__ xout,
    const int* __restrict__ off, const int2* __restrict__ edges,
    float alpha, float beta, int has_z)
{
    unsigned int l = blockIdx.x;          // 0..16383
    int xcd  = l & 7;
    unsigned int s = l >> 3;              // 0..2047
    int bhi  = s >> 9;                    // 0..3
    int ntile = s & 511;                  // 0..511
    int b = bhi * 8 + xcd;

    int t = threadIdx.x;
    int n = ntile * 32 + (t >> 3);
    unsigned int dgb = (unsigned int)(t & 7) * 16u;   // byte offset of d-group
    int e0 = off[n], e1 = off[n + 1];
    const char* xbB = (const char*)(xin + (size_t)b * NN * DD);

    float acc[8];
#pragma unroll
    for (int j = 0; j < 8; j++) acc[j] = 0.f;

#define FMA8(V, W)                                                        \
    do {                                                                  \
        acc[0] = fmaf((W), __uint_as_float((V).x << 16), acc[0]);         \
        acc[1] = fmaf((W), __uint_as_float((V).x & 0xffff0000u), acc[1]); \
        acc[2] = fmaf((W), __uint_as_float((V).y << 16), acc[2]);         \
        acc[3] = fmaf((W), __uint_as_float((V).y & 0xffff0000u), acc[3]); \
        acc[4] = fmaf((W), __uint_as_float((V).z << 16), acc[4]);         \
        acc[5] = fmaf((W), __uint_as_float((V).z & 0xffff0000u), acc[5]); \
        acc[6] = fmaf((W), __uint_as_float((V).w << 16), acc[6]);         \
        acc[7] = fmaf((W), __uint_as_float((V).w & 0xffff0000u), acc[7]); \
    } while (0)

    int ecnt = e1 - e0;
    int nb4 = ecnt >> 2;          // number of full groups of 4 edges

    int2 ed0, ed1, ed2, ed3;
    if (nb4 > 0) {
        ed0 = edges[e0];
        ed1 = edges[e0 + 1];
        ed2 = edges[e0 + 2];
        ed3 = edges[e0 + 3];
    }
    for (int it = 0; it < nb4; ++it) {
        // 4 independent gathers in flight
        uint4 v0 = *(const uint4*)(xbB + (((unsigned int)ed0.x) << 7) + dgb);
        uint4 v1 = *(const uint4*)(xbB + (((unsigned int)ed1.x) << 7) + dgb);
        uint4 v2 = *(const uint4*)(xbB + (((unsigned int)ed2.x) << 7) + dgb);
        uint4 v3 = *(const uint4*)(xbB + (((unsigned int)ed3.x) << 7) + dgb);
        float w0 = __int_as_float(ed0.y);
        float w1 = __int_as_float(ed1.y);
        float w2 = __int_as_float(ed2.y);
        float w3 = __int_as_float(ed3.y);

        // prefetch next group's edge tuples (hides edge-load latency under FMAs)
        int2 nd0, nd1, nd2, nd3;
        int enext = e0 + (it + 1) * 4;
        if (it + 1 < nb4) {
            nd0 = edges[enext];
            nd1 = edges[enext + 1];
            nd2 = edges[enext + 2];
            nd3 = edges[enext + 3];
        }

        FMA8(v0, w0);
        FMA8(v1, w1);
        FMA8(v2, w2);
        FMA8(v3, w3);

        ed0 = nd0; ed1 = nd1; ed2 = nd2; ed3 = nd3;
    }
    // tail (<= 3 edges)
    for (int e = e0 + nb4 * 4; e < e1; ++e) {
        int2 ed = edges[e];
        float wv = __int_as_float(ed.y);
        uint4 v = *(const uint4*)(xbB + (((unsigned int)ed.x) << 7) + dgb);
        FMA8(v, wv);
    }
#undef FMA8

    size_t fo = ((size_t)b * NN + n) * DD + (dgb >> 1);
    if (has_z) {
        uint4 zv = *(const uint4*)(z + fo);
        float zf[8];
        zf[0] = __uint_as_float(zv.x << 16);
        zf[1] = __uint_as_float(zv.x & 0xffff0000u);
        zf[2] = __uint_as_float(zv.y << 16);
        zf[3] = __uint_as_float(zv.y & 0xffff0000u);
        zf[4] = __uint_as_float(zv.z << 16);
        zf[5] = __uint_as_float(zv.z & 0xffff0000u);
        zf[6] = __uint_as_float(zv.w << 16);
        zf[7] = __uint_as_float(zv.w & 0xffff0000u);
#pragma unroll
        for (int j = 0; j < 8; j++) acc[j] = alpha * acc[j] + beta * zf[j];
    }

    uint4 o;
    o.x = pack2(acc[0], acc[1]);
    o.y = pack2(acc[2], acc[3]);
    o.z = pack2(acc[4], acc[5]);
    o.w = pack2(acc[6], acc[7]);
    *(uint4*)(xout + fo) = o;
}

// ---------------------------------------------------------------- final GEMM (MFMA)
// No-LDS streaming version. Block = 256 rows (4 waves x 64 rows), grid 2048.
// Each wave: 4 row-tiles of 16 -> acc[4 ct][4 rt], 160 MFMA/wave.
// A fragments load 16B/lane directly from the X arrays: row stride 128 B,
// each 128-B line consumed by 4 quads x 2 k-halves within the same wave
// (L1-resident reuse) — LDS staging + barrier was pure overhead at 3 blk/CU.
// B fragments (Wt, 40 KB) are L1/L2-hot and amortized over 4 row-tiles.
// __launch_bounds__(256,4): cap VGPR at 128 -> 4 waves/SIMD (50% occupancy).
__global__ __launch_bounds__(256, 4) void final_mfma(
    const unsigned short* __restrict__ X0, const unsigned short* __restrict__ X1,
    const unsigned short* __restrict__ X2, const unsigned short* __restrict__ X3,
    const unsigned short* __restrict__ X4,
    const unsigned short* __restrict__ Wt, const float* __restrict__ bias,
    float* __restrict__ out)
{
    int blk = blockIdx.x;              // 0..2047
    int b = blk >> 6;                  // 0..31
    int n0 = (blk & 63) * 256;         // 0..16128
    int t = threadIdx.x;
    int wave = t >> 6;
    int lane = t & 63;
    int col = lane & 15;
    int quad = lane >> 4;

    size_t rowbase = (size_t)b * NN + n0 + wave * 64;   // this wave's 64 rows

    floatx4 acc[4][4];                 // [ct][rt]
#pragma unroll
    for (int ct = 0; ct < 4; ct++)
#pragma unroll
        for (int rt = 0; rt < 4; rt++) acc[ct][rt] = (floatx4){0.f, 0.f, 0.f, 0.f};

    // One K-step: m selects the X array, h selects the 32-elem half of the
    // 64-elem D dim. k' (Wt k-index) = (m*2+h)*32 + quad*8. All indices static.
#define KSTEP(XP, m, h)                                                          \
    {                                                                            \
        const unsigned short* xa = (XP) + rowbase * DD + (h) * 32 + quad * 8;    \
        short8 a0 = *(const short8*)(xa + (0 * 16 + col) * DD);                  \
        short8 a1 = *(const short8*)(xa + (1 * 16 + col) * DD);                  \
        short8 a2 = *(const short8*)(xa + (2 * 16 + col) * DD);                  \
        short8 a3 = *(const short8*)(xa + (3 * 16 + col) * DD);                  \
        const unsigned short* wb = Wt + ((m) * 2 + (h)) * 32 + quad * 8;         \
        short8 b0 = *(const short8*)(wb + (0 * 16 + col) * KK);                  \
        short8 b1 = *(const short8*)(wb + (1 * 16 + col) * KK);                  \
        short8 b2 = *(const short8*)(wb + (2 * 16 + col) * KK);                  \
        short8 b3 = *(const short8*)(wb + (3 * 16 + col) * KK);                  \
        acc[0][0] = __builtin_amdgcn_mfma_f32_16x16x32_bf16(a0, b0, acc[0][0], 0, 0, 0); \
        acc[0][1] = __builtin_amdgcn_mfma_f32_16x16x32_bf16(a1, b0, acc[0][1], 0, 0, 0); \
        acc[0][2] = __builtin_amdgcn_mfma_f32_16x16x32_bf16(a2, b0, acc[0][2], 0, 0, 0); \
        acc[0][3] = __builtin_amdgcn_mfma_f32_16x16x32_bf16(a3, b0, acc[0][3], 0, 0, 0); \
        acc[1][0] = __builtin_amdgcn_mfma_f32_16x16x32_bf16(a0, b1, acc[1][0], 0, 0, 0); \
        acc[1][1] = __builtin_amdgcn_mfma_f32_16x16x32_bf16(a1, b1, acc[1][1], 0, 0, 0); \
        acc[1][2] = __builtin_amdgcn_mfma_f32_16x16x32_bf16(a2, b1, acc[1][2], 0, 0, 0); \
        acc[1][3] = __builtin_amdgcn_mfma_f32_16x16x32_bf16(a3, b1, acc[1][3], 0, 0, 0); \
        acc[2][0] = __builtin_amdgcn_mfma_f32_16x16x32_bf16(a0, b2, acc[2][0], 0, 0, 0); \
        acc[2][1] = __builtin_amdgcn_mfma_f32_16x16x32_bf16(a1, b2, acc[2][1], 0, 0, 0); \
        acc[2][2] = __builtin_amdgcn_mfma_f32_16x16x32_bf16(a2, b2, acc[2][2], 0, 0, 0); \
        acc[2][3] = __builtin_amdgcn_mfma_f32_16x16x32_bf16(a3, b2, acc[2][3], 0, 0, 0); \
        acc[3][0] = __builtin_amdgcn_mfma_f32_16x16x32_bf16(a0, b3, acc[3][0], 0, 0, 0); \
        acc[3][1] = __builtin_amdgcn_mfma_f32_16x16x32_bf16(a1, b3, acc[3][1], 0, 0, 0); \
        acc[3][2] = __builtin_amdgcn_mfma_f32_16x16x32_bf16(a2, b3, acc[3][2], 0, 0, 0); \
        acc[3][3] = __builtin_amdgcn_mfma_f32_16x16x32_bf16(a3, b3, acc[3][3], 0, 0, 0); \
    }

    KSTEP(X0, 0, 0)
    KSTEP(X0, 0, 1)
    KSTEP(X1, 1, 0)
    KSTEP(X1, 1, 1)
    KSTEP(X2, 2, 0)
    KSTEP(X2, 2, 1)
    KSTEP(X3, 3, 0)
    KSTEP(X3, 3, 1)
    KSTEP(X4, 4, 0)
    KSTEP(X4, 4, 1)
#undef KSTEP

#pragma unroll
    for (int ct = 0; ct < 4; ct++) {
        int o = ct * 16 + col;
        float bv = bias[o];
#pragma unroll
        for (int rt = 0; rt < 4; rt++) {
            size_t rb = rowbase + rt * 16 + quad * 4;
#pragma unroll
            for (int r = 0; r < 4; r++) {
                out[(rb + r) * OO + o] = acc[ct][rt][r] + bv;
            }
        }
    }
}

// ---------------------------------------------------------------- launch
extern "C" void kernel_launch(void* const* d_in, const int* in_sizes, int n_in,
                              void* d_out, int out_size, void* d_ws, size_t ws_size,
                              hipStream_t stream)
{
    (void)in_sizes; (void)n_in; (void)out_size; (void)ws_size;
    const float* inputs  = (const float*)d_in[0];
    const float* adj     = (const float*)d_in[1];
    const int*   rows    = (const int*)d_in[2];
    const int*   cols    = (const int*)d_in[3];
    const float* weights = (const float*)d_in[4];
    const float* bias    = (const float*)d_in[5];
    float* out = (float*)d_out;

    char* ws = (char*)d_ws;
    size_t off = 0;
    auto alloc = [&](size_t bytes) -> char* {
        char* p = ws + off;
        off = (off + bytes + 255) & ~(size_t)255;
        return p;
    };
    float* drow    = (float*)alloc(NN * 4);
    float* dcol    = (float*)alloc(NN * 4);
    int* cnt_col   = (int*)alloc(NN * 4);
    int* cnt_row   = (int*)alloc(NN * 4);
    int* off_col   = (int*)alloc((NN + 1) * 4);
    int* off_row   = (int*)alloc((NN + 1) * 4);
    int* cur_col   = (int*)alloc(NN * 4);
    int* cur_row   = (int*)alloc(NN * 4);
    int2* edge1    = (int2*)alloc((size_t)EE * 8);
    int2* edge2    = (int2*)alloc((size_t)EE * 8);
    unsigned short* Wt = (unsigned short*)alloc((size_t)OO * KK * 2);
    unsigned short* X[MM];
    for (int m = 0; m < MM; m++) X[m] = (unsigned short*)alloc((size_t)NN * BB * DD * 2);

    // zero the atomic accumulators (drow,dcol,cnt_col,cnt_row are contiguous)
    hipMemsetAsync(drow, 0, (size_t)NN * 4 * 4, stream);

    hist_kernel<<<EE / 256, 256, 0, stream>>>(adj, rows, cols, drow, dcol,
                                              cnt_row, cnt_col);
    scan_kernel<<<2, 1024, 0, stream>>>(cnt_col, cnt_row, off_col, off_row,
                                        cur_col, cur_row);
    scatter_kernel<<<EE / 256, 256, 0, stream>>>(adj, rows, cols, drow, dcol,
                                                 cur_col, cur_row, edge1, edge2);
    cast_kernel<<<(BB * NN * DD) / (256 * 8), 256, 0, stream>>>(inputs, X[0]);
    wprep_kernel<<<(OO * KK + 255) / 256, 256, 0, stream>>>(weights, Wt);

    const int SPMM_GRID = 512 * BB;   // 512 node-tiles x 32 b, XCD-swizzled

    // xs1 = S1 x0
    spmm_kernel<<<SPMM_GRID, 256, 0, stream>>>(X[0], nullptr, X[1], off_col,
                                               edge1, 1.f, 0.f, 0);
    // xs2 = 2*S1 xs1 - x0
    spmm_kernel<<<SPMM_GRID, 256, 0, stream>>>(X[1], X[0], X[2], off_col,
                                               edge1, 2.f, -1.f, 1);
    // xs3 = S2 xs1   (x0 deliberately NOT reset between supports)
    spmm_kernel<<<SPMM_GRID, 256, 0, stream>>>(X[1], nullptr, X[3], off_row,
                                               edge2, 1.f, 0.f, 0);
    // xs4 = 2*S2 xs3 - xs1
    spmm_kernel<<<SPMM_GRID, 256, 0, stream>>>(X[3], X[1], X[4], off_row,
                                               edge2, 2.f, -1.f, 1);

    final_mfma<<<BB * (NN / 256), 256, 0, stream>>>(X[0], X[1], X[2], X[3], X[4],
                                                    Wt, bias, out);
}

// Round 3
// 1038.505 us; speedup vs baseline: 1.4382x; 1.0042x over previous
//
#include <hip/hip_runtime.h>
#include <stdint.h>

// Problem constants (fixed by the reference).
#define NN 16384      // nodes
#define EE 524288     // edges
#define BB 32         // batch
#define DD 64         // input dim
#define OO 64         // output dim
#define MM 5          // num diffusion matrices
#define KK 320        // D*M  (GEMM reduction dim)

typedef __attribute__((ext_vector_type(2))) _Float16 half2_t;
typedef __attribute__((ext_vector_type(8))) _Float16 half8_t;
typedef __attribute__((ext_vector_type(4))) float floatx4;

// ---------------------------------------------------------------- histogram
__global__ __launch_bounds__(256) void hist_kernel(
    const float* __restrict__ adj, const int* __restrict__ rows,
    const int* __restrict__ cols,
    float* __restrict__ drow, float* __restrict__ dcol,
    int* __restrict__ cnt_row, int* __restrict__ cnt_col)
{
    int e = blockIdx.x * 256 + threadIdx.x;
    if (e < EE) {
        float a = adj[e];
        int r = rows[e], c = cols[e];
        atomicAdd(&drow[r], a);
        atomicAdd(&dcol[c], a);
        atomicAdd(&cnt_row[r], 1);
        atomicAdd(&cnt_col[c], 1);
    }
}

// ---------------------------------------------------------------- scan
// One block per array (grid=2), 1024 threads, 16 elements/thread.
__global__ __launch_bounds__(1024) void scan_kernel(
    const int* __restrict__ cnt_col, const int* __restrict__ cnt_row,
    int* __restrict__ off_col, int* __restrict__ off_row,
    int* __restrict__ cur_col, int* __restrict__ cur_row)
{
    const int* cnt = (blockIdx.x == 0) ? cnt_col : cnt_row;
    int* off = (blockIdx.x == 0) ? off_col : off_row;
    int* cur = (blockIdx.x == 0) ? cur_col : cur_row;

    __shared__ int part[1024];
    int t = threadIdx.x;
    int base = t * 16;
    int local[16];
    int s = 0;
#pragma unroll
    for (int i = 0; i < 16; i++) { local[i] = cnt[base + i]; s += local[i]; }
    part[t] = s;
    __syncthreads();
    for (int d = 1; d < 1024; d <<= 1) {
        int v = (t >= d) ? part[t - d] : 0;
        __syncthreads();
        part[t] += v;
        __syncthreads();
    }
    int run = (t == 0) ? 0 : part[t - 1];
#pragma unroll
    for (int i = 0; i < 16; i++) {
        off[base + i] = run;
        cur[base + i] = run;
        run += local[i];
    }
    if (t == 1023) off[NN] = run;
}

// ---------------------------------------------------------------- scatter
// Builds packed CSR edge arrays: edge[e] = {src, half2(w,w)}
__global__ __launch_bounds__(256) void scatter_kernel(
    const float* __restrict__ adj, const int* __restrict__ rows,
    const int* __restrict__ cols,
    const float* __restrict__ drow, const float* __restrict__ dcol,
    int* __restrict__ cur_col, int* __restrict__ cur_row,
    int2* __restrict__ edge1, int2* __restrict__ edge2)
{
    int e = blockIdx.x * 256 + threadIdx.x;
    if (e < EE) {
        float a = adj[e];
        int r = rows[e], c = cols[e];
        float dr = drow[r];
        float idr = (dr > 0.f) ? (1.f / dr) : 0.f;
        float dc = dcol[c];
        float idc = (dc > 0.f) ? (1.f / dc) : 0.f;
        _Float16 h1 = (_Float16)(a * idr);
        _Float16 h2 = (_Float16)(a * idc);
        unsigned short u1 = __builtin_bit_cast(unsigned short, h1);
        unsigned short u2 = __builtin_bit_cast(unsigned short, h2);
        int p1 = atomicAdd(&cur_col[c], 1);   // support1: dst=cols, src=rows
        edge1[p1] = make_int2(r, (int)(u1 | ((unsigned int)u1 << 16)));
        int p2 = atomicAdd(&cur_row[r], 1);   // support2: dst=rows, src=cols
        edge2[p2] = make_int2(c, (int)(u2 | ((unsigned int)u2 << 16)));
    }
}

// ---------------------------------------------------------------- cast
// inputs [B,N,D] fp32 -> x0 [B,N,D] fp16
__global__ __launch_bounds__(256) void cast_kernel(
    const float* __restrict__ inp, unsigned short* __restrict__ x0)
{
    size_t i = ((size_t)blockIdx.x * 256 + threadIdx.x) * 8;
    float4 a = *(const float4*)(inp + i);
    float4 b = *(const float4*)(inp + i + 4);
    half2_t h0 = {(_Float16)a.x, (_Float16)a.y};
    half2_t h1 = {(_Float16)a.z, (_Float16)a.w};
    half2_t h2 = {(_Float16)b.x, (_Float16)b.y};
    half2_t h3 = {(_Float16)b.z, (_Float16)b.w};
    uint4 o;
    o.x = __builtin_bit_cast(unsigned int, h0);
    o.y = __builtin_bit_cast(unsigned int, h1);
    o.z = __builtin_bit_cast(unsigned int, h2);
    o.w = __builtin_bit_cast(unsigned int, h3);
    *(uint4*)(x0 + i) = o;
}

// ---------------------------------------------------------------- W prep
// Wt[o][k'] fp16 with k' = m*64 + d
__global__ __launch_bounds__(256) void wprep_kernel(
    const float* __restrict__ W, unsigned short* __restrict__ Wt)
{
    int i = blockIdx.x * 256 + threadIdx.x;
    if (i < OO * KK) {
        int o = i / KK;
        int kp = i - o * KK;
        int m = kp >> 6;
        int d = kp & 63;
        _Float16 h = (_Float16)W[(d * MM + m) * OO + o];
        Wt[i] = __builtin_bit_cast(unsigned short, h);
    }
}

// ---------------------------------------------------------------- spmm
// One block = 32 dst nodes x ONE batch slice b. Thread t: node = n0+(t>>3),
// d-group = (t&7)*8 (one uint4 = 128B segment per edge per 8-lane group).
// XCD swizzle: blkid&7 selects XCD; b = bhi*8 + xcd so all concurrent blocks
// on an XCD share one 2 MB X b-slice (captured in that XCD's 4 MB L2).
// Edge loop software-pipelined in groups of 4 (4 gathers in flight; next
// group's edge tuples prefetched under the FMA block).
// fp16 packed math: per edge = 4 x v_pk_fma_f16, zero unpack ops.
__global__ __launch_bounds__(256) void spmm_kernel(
    const unsigned short* __restrict__ xin,
    const unsigned short* __restrict__ z,
    unsigned short* __restrict__ xout,
    const int* __restrict__ off, const int2* __restrict__ edges,
    float alpha, float beta, int has_z)
{
    unsigned int l = blockIdx.x;          // 0..16383
    int xcd  = l & 7;
    unsigned int s = l >> 3;              // 0..2047
    int bhi  = s >> 9;                    // 0..3
    int ntile = s & 511;                  // 0..511
    int b = bhi * 8 + xcd;

    int t = threadIdx.x;
    int n = ntile * 32 + (t >> 3);
    unsigned int dgb = (unsigned int)(t & 7) * 16u;   // byte offset of d-group
    int e0 = off[n], e1 = off[n + 1];
    const char* xbB = (const char*)(xin + (size_t)b * NN * DD);

    half2_t acc0 = (half2_t)0, acc1 = (half2_t)0, acc2 = (half2_t)0, acc3 = (half2_t)0;

#define FMA4(V, W2)                                                       \
    do {                                                                  \
        acc0 = __builtin_bit_cast(half2_t, (V).x) * (W2) + acc0;          \
        acc1 = __builtin_bit_cast(half2_t, (V).y) * (W2) + acc1;          \
        acc2 = __builtin_bit_cast(half2_t, (V).z) * (W2) + acc2;          \
        acc3 = __builtin_bit_cast(half2_t, (V).w) * (W2) + acc3;          \
    } while (0)

    int ecnt = e1 - e0;
    int nb4 = ecnt >> 2;          // number of full groups of 4 edges

    int2 ed0, ed1, ed2, ed3;
    if (nb4 > 0) {
        ed0 = edges[e0];
        ed1 = edges[e0 + 1];
        ed2 = edges[e0 + 2];
        ed3 = edges[e0 + 3];
    }
    for (int it = 0; it < nb4; ++it) {
        // 4 independent gathers in flight
        uint4 v0 = *(const uint4*)(xbB + (((unsigned int)ed0.x) << 7) + dgb);
        uint4 v1 = *(const uint4*)(xbB + (((unsigned int)ed1.x) << 7) + dgb);
        uint4 v2 = *(const uint4*)(xbB + (((unsigned int)ed2.x) << 7) + dgb);
        uint4 v3 = *(const uint4*)(xbB + (((unsigned int)ed3.x) << 7) + dgb);
        half2_t w0 = __builtin_bit_cast(half2_t, ed0.y);
        half2_t w1 = __builtin_bit_cast(half2_t, ed1.y);
        half2_t w2 = __builtin_bit_cast(half2_t, ed2.y);
        half2_t w3 = __builtin_bit_cast(half2_t, ed3.y);

        // prefetch next group's edge tuples (hides edge-load latency under FMAs)
        int2 nd0, nd1, nd2, nd3;
        int enext = e0 + (it + 1) * 4;
        if (it + 1 < nb4) {
            nd0 = edges[enext];
            nd1 = edges[enext + 1];
            nd2 = edges[enext + 2];
            nd3 = edges[enext + 3];
        }

        FMA4(v0, w0);
        FMA4(v1, w1);
        FMA4(v2, w2);
        FMA4(v3, w3);

        ed0 = nd0; ed1 = nd1; ed2 = nd2; ed3 = nd3;
    }
    // tail (<= 3 edges)
    for (int e = e0 + nb4 * 4; e < e1; ++e) {
        int2 ed = edges[e];
        half2_t wv = __builtin_bit_cast(half2_t, ed.y);
        uint4 v = *(const uint4*)(xbB + (((unsigned int)ed.x) << 7) + dgb);
        FMA4(v, wv);
    }
#undef FMA4

    size_t fo = ((size_t)b * NN + n) * DD + (dgb >> 1);
    if (has_z) {
        uint4 zv = *(const uint4*)(z + fo);
        half2_t al = {(_Float16)alpha, (_Float16)alpha};
        half2_t be = {(_Float16)beta, (_Float16)beta};
        acc0 = al * acc0 + be * __builtin_bit_cast(half2_t, zv.x);
        acc1 = al * acc1 + be * __builtin_bit_cast(half2_t, zv.y);
        acc2 = al * acc2 + be * __builtin_bit_cast(half2_t, zv.z);
        acc3 = al * acc3 + be * __builtin_bit_cast(half2_t, zv.w);
    }

    uint4 o;
    o.x = __builtin_bit_cast(unsigned int, acc0);
    o.y = __builtin_bit_cast(unsigned int, acc1);
    o.z = __builtin_bit_cast(unsigned int, acc2);
    o.w = __builtin_bit_cast(unsigned int, acc3);
    *(uint4*)(xout + fo) = o;
}

// ---------------------------------------------------------------- final GEMM (MFMA)
// No-LDS streaming version. Block = 256 rows (4 waves x 64 rows), grid 2048.
// Each wave: 4 row-tiles of 16 -> acc[4 ct][4 rt], 160 MFMA/wave.
// A fragments load 16B/lane directly from the X arrays (fp16), B from Wt.
// __launch_bounds__(256,4): cap VGPR at 128 -> 4 waves/SIMD (50% occupancy).
__global__ __launch_bounds__(256, 4) void final_mfma(
    const unsigned short* __restrict__ X0, const unsigned short* __restrict__ X1,
    const unsigned short* __restrict__ X2, const unsigned short* __restrict__ X3,
    const unsigned short* __restrict__ X4,
    const unsigned short* __restrict__ Wt, const float* __restrict__ bias,
    float* __restrict__ out)
{
    int blk = blockIdx.x;              // 0..2047
    int b = blk >> 6;                  // 0..31
    int n0 = (blk & 63) * 256;         // 0..16128
    int t = threadIdx.x;
    int wave = t >> 6;
    int lane = t & 63;
    int col = lane & 15;
    int quad = lane >> 4;

    size_t rowbase = (size_t)b * NN + n0 + wave * 64;   // this wave's 64 rows

    floatx4 acc[4][4];                 // [ct][rt]
#pragma unroll
    for (int ct = 0; ct < 4; ct++)
#pragma unroll
        for (int rt = 0; rt < 4; rt++) acc[ct][rt] = (floatx4){0.f, 0.f, 0.f, 0.f};

    // One K-step: m selects the X array, h selects the 32-elem half of the
    // 64-elem D dim. k' (Wt k-index) = (m*2+h)*32 + quad*8. All indices static.
#define KSTEP(XP, m, h)                                                          \
    {                                                                            \
        const unsigned short* xa = (XP) + rowbase * DD + (h) * 32 + quad * 8;    \
        half8_t a0 = *(const half8_t*)(xa + (0 * 16 + col) * DD);                \
        half8_t a1 = *(const half8_t*)(xa + (1 * 16 + col) * DD);                \
        half8_t a2 = *(const half8_t*)(xa + (2 * 16 + col) * DD);                \
        half8_t a3 = *(const half8_t*)(xa + (3 * 16 + col) * DD);                \
        const unsigned short* wb = Wt + ((m) * 2 + (h)) * 32 + quad * 8;         \
        half8_t b0 = *(const half8_t*)(wb + (0 * 16 + col) * KK);                \
        half8_t b1 = *(const half8_t*)(wb + (1 * 16 + col) * KK);                \
        half8_t b2 = *(const half8_t*)(wb + (2 * 16 + col) * KK);                \
        half8_t b3 = *(const half8_t*)(wb + (3 * 16 + col) * KK);                \
        acc[0][0] = __builtin_amdgcn_mfma_f32_16x16x32_f16(a0, b0, acc[0][0], 0, 0, 0); \
        acc[0][1] = __builtin_amdgcn_mfma_f32_16x16x32_f16(a1, b0, acc[0][1], 0, 0, 0); \
        acc[0][2] = __builtin_amdgcn_mfma_f32_16x16x32_f16(a2, b0, acc[0][2], 0, 0, 0); \
        acc[0][3] = __builtin_amdgcn_mfma_f32_16x16x32_f16(a3, b0, acc[0][3], 0, 0, 0); \
        acc[1][0] = __builtin_amdgcn_mfma_f32_16x16x32_f16(a0, b1, acc[1][0], 0, 0, 0); \
        acc[1][1] = __builtin_amdgcn_mfma_f32_16x16x32_f16(a1, b1, acc[1][1], 0, 0, 0); \
        acc[1][2] = __builtin_amdgcn_mfma_f32_16x16x32_f16(a2, b1, acc[1][2], 0, 0, 0); \
        acc[1][3] = __builtin_amdgcn_mfma_f32_16x16x32_f16(a3, b1, acc[1][3], 0, 0, 0); \
        acc[2][0] = __builtin_amdgcn_mfma_f32_16x16x32_f16(a0, b2, acc[2][0], 0, 0, 0); \
        acc[2][1] = __builtin_amdgcn_mfma_f32_16x16x32_f16(a1, b2, acc[2][1], 0, 0, 0); \
        acc[2][2] = __builtin_amdgcn_mfma_f32_16x16x32_f16(a2, b2, acc[2][2], 0, 0, 0); \
        acc[2][3] = __builtin_amdgcn_mfma_f32_16x16x32_f16(a3, b2, acc[2][3], 0, 0, 0); \
        acc[3][0] = __builtin_amdgcn_mfma_f32_16x16x32_f16(a0, b3, acc[3][0], 0, 0, 0); \
        acc[3][1] = __builtin_amdgcn_mfma_f32_16x16x32_f16(a1, b3, acc[3][1], 0, 0, 0); \
        acc[3][2] = __builtin_amdgcn_mfma_f32_16x16x32_f16(a2, b3, acc[3][2], 0, 0, 0); \
        acc[3][3] = __builtin_amdgcn_mfma_f32_16x16x32_f16(a3, b3, acc[3][3], 0, 0, 0); \
    }

    KSTEP(X0, 0, 0)
    KSTEP(X0, 0, 1)
    KSTEP(X1, 1, 0)
    KSTEP(X1, 1, 1)
    KSTEP(X2, 2, 0)
    KSTEP(X2, 2, 1)
    KSTEP(X3, 3, 0)
    KSTEP(X3, 3, 1)
    KSTEP(X4, 4, 0)
    KSTEP(X4, 4, 1)
#undef KSTEP

#pragma unroll
    for (int ct = 0; ct < 4; ct++) {
        int o = ct * 16 + col;
        float bv = bias[o];
#pragma unroll
        for (int rt = 0; rt < 4; rt++) {
            size_t rb = rowbase + rt * 16 + quad * 4;
#pragma unroll
            for (int r = 0; r < 4; r++) {
                out[(rb + r) * OO + o] = acc[ct][rt][r] + bv;
            }
        }
    }
}

// ---------------------------------------------------------------- launch
extern "C" void kernel_launch(void* const* d_in, const int* in_sizes, int n_in,
                              void* d_out, int out_size, void* d_ws, size_t ws_size,
                              hipStream_t stream)
{
    (void)in_sizes; (void)n_in; (void)out_size; (void)ws_size;
    const float* inputs  = (const float*)d_in[0];
    const float* adj     = (const float*)d_in[1];
    const int*   rows    = (const int*)d_in[2];
    const int*   cols    = (const int*)d_in[3];
    const float* weights = (const float*)d_in[4];
    const float* bias    = (const float*)d_in[5];
    float* out = (float*)d_out;

    char* ws = (char*)d_ws;
    size_t off = 0;
    auto alloc = [&](size_t bytes) -> char* {
        char* p = ws + off;
        off = (off + bytes + 255) & ~(size_t)255;
        return p;
    };
    float* drow    = (float*)alloc(NN * 4);
    float* dcol    = (float*)alloc(NN * 4);
    int* cnt_col   = (int*)alloc(NN * 4);
    int* cnt_row   = (int*)alloc(NN * 4);
    int* off_col   = (int*)alloc((NN + 1) * 4);
    int* off_row   = (int*)alloc((NN + 1) * 4);
    int* cur_col   = (int*)alloc(NN * 4);
    int* cur_row   = (int*)alloc(NN * 4);
    int2* edge1    = (int2*)alloc((size_t)EE * 8);
    int2* edge2    = (int2*)alloc((size_t)EE * 8);
    unsigned short* Wt = (unsigned short*)alloc((size_t)OO * KK * 2);
    unsigned short* X[MM];
    for (int m = 0; m < MM; m++) X[m] = (unsigned short*)alloc((size_t)NN * BB * DD * 2);

    // zero the atomic accumulators (drow,dcol,cnt_col,cnt_row are contiguous)
    hipMemsetAsync(drow, 0, (size_t)NN * 4 * 4, stream);

    hist_kernel<<<EE / 256, 256, 0, stream>>>(adj, rows, cols, drow, dcol,
                                              cnt_row, cnt_col);
    scan_kernel<<<2, 1024, 0, stream>>>(cnt_col, cnt_row, off_col, off_row,
                                        cur_col, cur_row);
    scatter_kernel<<<EE / 256, 256, 0, stream>>>(adj, rows, cols, drow, dcol,
                                                 cur_col, cur_row, edge1, edge2);
    cast_kernel<<<(BB * NN * DD) / (256 * 8), 256, 0, stream>>>(inputs, X[0]);
    wprep_kernel<<<(OO * KK + 255) / 256, 256, 0, stream>>>(weights, Wt);

    const int SPMM_GRID = 512 * BB;   // 512 node-tiles x 32 b, XCD-swizzled

    // xs1 = S1 x0
    spmm_kernel<<<SPMM_GRID, 256, 0, stream>>>(X[0], nullptr, X[1], off_col,
                                               edge1, 1.f, 0.f, 0);
    // xs2 = 2*S1 xs1 - x0
    spmm_kernel<<<SPMM_GRID, 256, 0, stream>>>(X[1], X[0], X[2], off_col,
                                               edge1, 2.f, -1.f, 1);
    // xs3 = S2 xs1   (x0 deliberately NOT reset between supports)
    spmm_kernel<<<SPMM_GRID, 256, 0, stream>>>(X[1], nullptr, X[3], off_row,
                                               edge2, 1.f, 0.f, 0);
    // xs4 = 2*S2 xs3 - xs1
    spmm_kernel<<<SPMM_GRID, 256, 0, stream>>>(X[3], X[1], X[4], off_row,
                                               edge2, 2.f, -1.f, 1);

    final_mfma<<<BB * (NN / 256), 256, 0, stream>>>(X[0], X[1], X[2], X[3], X[4],
                                                    Wt, bias, out);
}

// Round 4
// 1024.983 us; speedup vs baseline: 1.4571x; 1.0132x over previous
//
#include <hip/hip_runtime.h>
#include <stdint.h>

// Problem constants (fixed by the reference).
#define NN 16384      // nodes
#define EE 524288     // edges
#define BB 32         // batch
#define DD 64         // input dim
#define OO 64         // output dim
#define MM 5          // num diffusion matrices
#define KK 320        // D*M  (GEMM reduction dim)

typedef __attribute__((ext_vector_type(2))) _Float16 half2_t;
typedef __attribute__((ext_vector_type(8))) _Float16 half8_t;
typedef __attribute__((ext_vector_type(4))) float floatx4;

// ---------------------------------------------------------------- histogram
__global__ __launch_bounds__(256) void hist_kernel(
    const float* __restrict__ adj, const int* __restrict__ rows,
    const int* __restrict__ cols,
    float* __restrict__ drow, float* __restrict__ dcol,
    int* __restrict__ cnt_row, int* __restrict__ cnt_col)
{
    int e = blockIdx.x * 256 + threadIdx.x;
    if (e < EE) {
        float a = adj[e];
        int r = rows[e], c = cols[e];
        atomicAdd(&drow[r], a);
        atomicAdd(&dcol[c], a);
        atomicAdd(&cnt_row[r], 1);
        atomicAdd(&cnt_col[c], 1);
    }
}

// ---------------------------------------------------------------- scan
// One block per array (grid=2), 1024 threads, 16 elements/thread.
__global__ __launch_bounds__(1024) void scan_kernel(
    const int* __restrict__ cnt_col, const int* __restrict__ cnt_row,
    int* __restrict__ off_col, int* __restrict__ off_row,
    int* __restrict__ cur_col, int* __restrict__ cur_row)
{
    const int* cnt = (blockIdx.x == 0) ? cnt_col : cnt_row;
    int* off = (blockIdx.x == 0) ? off_col : off_row;
    int* cur = (blockIdx.x == 0) ? cur_col : cur_row;

    __shared__ int part[1024];
    int t = threadIdx.x;
    int base = t * 16;
    int local[16];
    int s = 0;
#pragma unroll
    for (int i = 0; i < 16; i++) { local[i] = cnt[base + i]; s += local[i]; }
    part[t] = s;
    __syncthreads();
    for (int d = 1; d < 1024; d <<= 1) {
        int v = (t >= d) ? part[t - d] : 0;
        __syncthreads();
        part[t] += v;
        __syncthreads();
    }
    int run = (t == 0) ? 0 : part[t - 1];
#pragma unroll
    for (int i = 0; i < 16; i++) {
        off[base + i] = run;
        cur[base + i] = run;
        run += local[i];
    }
    if (t == 1023) off[NN] = run;
}

// ---------------------------------------------------------------- degree sort
// Counting-sort node ids by CSR degree (clamp 511). One block per array.
// Waves in spmm then cover ~equal-degree nodes -> no max-of-8 divergence tax.
// Order within a degree bin is arbitrary (atomic race) — per-node results are
// unchanged (each node's own edge order is untouched).
__global__ __launch_bounds__(1024) void degsort_kernel(
    const int* __restrict__ off_col, const int* __restrict__ off_row,
    int* __restrict__ perm_col, int* __restrict__ perm_row)
{
    const int* off = (blockIdx.x == 0) ? off_col : off_row;
    int* perm = (blockIdx.x == 0) ? perm_col : perm_row;

    __shared__ int bins[512];
    __shared__ int cur[512];
    int t = threadIdx.x;
    if (t < 512) bins[t] = 0;
    __syncthreads();
    for (int i = t; i < NN; i += 1024) {
        int d = off[i + 1] - off[i];
        if (d > 511) d = 511;
        atomicAdd(&bins[d], 1);
    }
    __syncthreads();
    // inclusive scan over 512 bins (Hillis-Steele, barriers wave-uniform)
    for (int sh = 1; sh < 512; sh <<= 1) {
        int v = (t < 512 && t >= sh) ? bins[t - sh] : 0;
        __syncthreads();
        if (t < 512) bins[t] += v;
        __syncthreads();
    }
    if (t < 512) cur[t] = (t == 0) ? 0 : bins[t - 1];
    __syncthreads();
    for (int i = t; i < NN; i += 1024) {
        int d = off[i + 1] - off[i];
        if (d > 511) d = 511;
        int p = atomicAdd(&cur[d], 1);
        perm[p] = i;
    }
}

// ---------------------------------------------------------------- scatter
// Builds packed CSR edge arrays: edge[e] = {src, half2(w,w)}
__global__ __launch_bounds__(256) void scatter_kernel(
    const float* __restrict__ adj, const int* __restrict__ rows,
    const int* __restrict__ cols,
    const float* __restrict__ drow, const float* __restrict__ dcol,
    int* __restrict__ cur_col, int* __restrict__ cur_row,
    int2* __restrict__ edge1, int2* __restrict__ edge2)
{
    int e = blockIdx.x * 256 + threadIdx.x;
    if (e < EE) {
        float a = adj[e];
        int r = rows[e], c = cols[e];
        float dr = drow[r];
        float idr = (dr > 0.f) ? (1.f / dr) : 0.f;
        float dc = dcol[c];
        float idc = (dc > 0.f) ? (1.f / dc) : 0.f;
        _Float16 h1 = (_Float16)(a * idr);
        _Float16 h2 = (_Float16)(a * idc);
        unsigned short u1 = __builtin_bit_cast(unsigned short, h1);
        unsigned short u2 = __builtin_bit_cast(unsigned short, h2);
        int p1 = atomicAdd(&cur_col[c], 1);   // support1: dst=cols, src=rows
        edge1[p1] = make_int2(r, (int)(u1 | ((unsigned int)u1 << 16)));
        int p2 = atomicAdd(&cur_row[r], 1);   // support2: dst=rows, src=cols
        edge2[p2] = make_int2(c, (int)(u2 | ((unsigned int)u2 << 16)));
    }
}

// ---------------------------------------------------------------- cast
// inputs [B,N,D] fp32 -> x0 [B,N,D] fp16
__global__ __launch_bounds__(256) void cast_kernel(
    const float* __restrict__ inp, unsigned short* __restrict__ x0)
{
    size_t i = ((size_t)blockIdx.x * 256 + threadIdx.x) * 8;
    float4 a = *(const float4*)(inp + i);
    float4 b = *(const float4*)(inp + i + 4);
    half2_t h0 = {(_Float16)a.x, (_Float16)a.y};
    half2_t h1 = {(_Float16)a.z, (_Float16)a.w};
    half2_t h2 = {(_Float16)b.x, (_Float16)b.y};
    half2_t h3 = {(_Float16)b.z, (_Float16)b.w};
    uint4 o;
    o.x = __builtin_bit_cast(unsigned int, h0);
    o.y = __builtin_bit_cast(unsigned int, h1);
    o.z = __builtin_bit_cast(unsigned int, h2);
    o.w = __builtin_bit_cast(unsigned int, h3);
    *(uint4*)(x0 + i) = o;
}

// ---------------------------------------------------------------- W prep
// Wt[o][k'] fp16 with k' = m*64 + d
__global__ __launch_bounds__(256) void wprep_kernel(
    const float* __restrict__ W, unsigned short* __restrict__ Wt)
{
    int i = blockIdx.x * 256 + threadIdx.x;
    if (i < OO * KK) {
        int o = i / KK;
        int kp = i - o * KK;
        int m = kp >> 6;
        int d = kp & 63;
        _Float16 h = (_Float16)W[(d * MM + m) * OO + o];
        Wt[i] = __builtin_bit_cast(unsigned short, h);
    }
}

// ---------------------------------------------------------------- spmm
// One block = 32 dst nodes x ONE batch slice b. Thread t: node =
// perm[ntile*32+(t>>3)] (degree-sorted), d-group = (t&7)*8.
// XCD swizzle: blkid&7 selects XCD; b = bhi*8 + xcd so all concurrent blocks
// on an XCD share one 2 MB X b-slice (captured in that XCD's 4 MB L2).
// 8-deep gather pipeline: 8 gathers in flight per wave; next-8 edge tuples
// prefetched branchlessly (clamped index) under the FMA block, so the
// compiler's waitcnt on v* leaves the edge loads outstanding.
__global__ __launch_bounds__(256) void spmm_kernel(
    const unsigned short* __restrict__ xin,
    const unsigned short* __restrict__ z,
    unsigned short* __restrict__ xout,
    const int* __restrict__ off, const int* __restrict__ perm,
    const int2* __restrict__ edges,
    float alpha, float beta, int has_z)
{
    unsigned int l = blockIdx.x;          // 0..16383
    int xcd  = l & 7;
    unsigned int s = l >> 3;              // 0..2047
    int bhi  = s >> 9;                    // 0..3
    int ntile = s & 511;                  // 0..511
    int b = bhi * 8 + xcd;

    int t = threadIdx.x;
    int n = perm[ntile * 32 + (t >> 3)];
    unsigned int dgb = (unsigned int)(t & 7) * 16u;   // byte offset of d-group
    int e0 = off[n], e1 = off[n + 1];
    const char* xbB = (const char*)(xin + (size_t)b * NN * DD);

    half2_t acc0 = (half2_t)0, acc1 = (half2_t)0, acc2 = (half2_t)0, acc3 = (half2_t)0;

#define GATHER(ED) (*(const uint4*)(xbB + (((unsigned int)(ED).x) << 7) + dgb))
#define FMA4(V, W2)                                                       \
    do {                                                                  \
        acc0 = __builtin_bit_cast(half2_t, (V).x) * (W2) + acc0;          \
        acc1 = __builtin_bit_cast(half2_t, (V).y) * (W2) + acc1;          \
        acc2 = __builtin_bit_cast(half2_t, (V).z) * (W2) + acc2;          \
        acc3 = __builtin_bit_cast(half2_t, (V).w) * (W2) + acc3;          \
    } while (0)

    int ecnt = e1 - e0;
    int nb8 = ecnt >> 3;          // number of full groups of 8 edges

    int2 ed0, ed1, ed2, ed3, ed4, ed5, ed6, ed7;
    if (nb8 > 0) {
        ed0 = edges[e0];     ed1 = edges[e0 + 1];
        ed2 = edges[e0 + 2]; ed3 = edges[e0 + 3];
        ed4 = edges[e0 + 4]; ed5 = edges[e0 + 5];
        ed6 = edges[e0 + 6]; ed7 = edges[e0 + 7];
    }
    for (int it = 0; it < nb8; ++it) {
        // 8 independent gathers in flight
        uint4 v0 = GATHER(ed0);
        uint4 v1 = GATHER(ed1);
        uint4 v2 = GATHER(ed2);
        uint4 v3 = GATHER(ed3);
        uint4 v4 = GATHER(ed4);
        uint4 v5 = GATHER(ed5);
        uint4 v6 = GATHER(ed6);
        uint4 v7 = GATHER(ed7);
        half2_t w0 = __builtin_bit_cast(half2_t, ed0.y);
        half2_t w1 = __builtin_bit_cast(half2_t, ed1.y);
        half2_t w2 = __builtin_bit_cast(half2_t, ed2.y);
        half2_t w3 = __builtin_bit_cast(half2_t, ed3.y);
        half2_t w4 = __builtin_bit_cast(half2_t, ed4.y);
        half2_t w5 = __builtin_bit_cast(half2_t, ed5.y);
        half2_t w6 = __builtin_bit_cast(half2_t, ed6.y);
        half2_t w7 = __builtin_bit_cast(half2_t, ed7.y);

        // branchless prefetch of next group's edge tuples (clamped on last it)
        int ep = (it + 1 < nb8) ? (e0 + (it + 1) * 8) : e0;
        int2 nd0 = edges[ep];     int2 nd1 = edges[ep + 1];
        int2 nd2 = edges[ep + 2]; int2 nd3 = edges[ep + 3];
        int2 nd4 = edges[ep + 4]; int2 nd5 = edges[ep + 5];
        int2 nd6 = edges[ep + 6]; int2 nd7 = edges[ep + 7];

        FMA4(v0, w0);
        FMA4(v1, w1);
        FMA4(v2, w2);
        FMA4(v3, w3);
        FMA4(v4, w4);
        FMA4(v5, w5);
        FMA4(v6, w6);
        FMA4(v7, w7);

        ed0 = nd0; ed1 = nd1; ed2 = nd2; ed3 = nd3;
        ed4 = nd4; ed5 = nd5; ed6 = nd6; ed7 = nd7;
    }
    // tail (<= 7 edges)
    for (int e = e0 + nb8 * 8; e < e1; ++e) {
        int2 ed = edges[e];
        half2_t wv = __builtin_bit_cast(half2_t, ed.y);
        uint4 v = GATHER(ed);
        FMA4(v, wv);
    }
#undef FMA4
#undef GATHER

    size_t fo = ((size_t)b * NN + n) * DD + (dgb >> 1);
    if (has_z) {
        uint4 zv = *(const uint4*)(z + fo);
        half2_t al = {(_Float16)alpha, (_Float16)alpha};
        half2_t be = {(_Float16)beta, (_Float16)beta};
        acc0 = al * acc0 + be * __builtin_bit_cast(half2_t, zv.x);
        acc1 = al * acc1 + be * __builtin_bit_cast(half2_t, zv.y);
        acc2 = al * acc2 + be * __builtin_bit_cast(half2_t, zv.z);
        acc3 = al * acc3 + be * __builtin_bit_cast(half2_t, zv.w);
    }

    uint4 o;
    o.x = __builtin_bit_cast(unsigned int, acc0);
    o.y = __builtin_bit_cast(unsigned int, acc1);
    o.z = __builtin_bit_cast(unsigned int, acc2);
    o.w = __builtin_bit_cast(unsigned int, acc3);
    *(uint4*)(xout + fo) = o;
}

// ---------------------------------------------------------------- final GEMM (MFMA)
// No-LDS streaming version. Block = 256 rows (4 waves x 64 rows), grid 2048.
// Each wave: 4 row-tiles of 16 -> acc[4 ct][4 rt], 160 MFMA/wave.
// A fragments load 16B/lane directly from the X arrays (fp16), B from Wt.
// __launch_bounds__(256,4): cap VGPR at 128 -> 4 waves/SIMD (50% occupancy).
__global__ __launch_bounds__(256, 4) void final_mfma(
    const unsigned short* __restrict__ X0, const unsigned short* __restrict__ X1,
    const unsigned short* __restrict__ X2, const unsigned short* __restrict__ X3,
    const unsigned short* __restrict__ X4,
    const unsigned short* __restrict__ Wt, const float* __restrict__ bias,
    float* __restrict__ out)
{
    int blk = blockIdx.x;              // 0..2047
    int b = blk >> 6;                  // 0..31
    int n0 = (blk & 63) * 256;         // 0..16128
    int t = threadIdx.x;
    int wave = t >> 6;
    int lane = t & 63;
    int col = lane & 15;
    int quad = lane >> 4;

    size_t rowbase = (size_t)b * NN + n0 + wave * 64;   // this wave's 64 rows

    floatx4 acc[4][4];                 // [ct][rt]
#pragma unroll
    for (int ct = 0; ct < 4; ct++)
#pragma unroll
        for (int rt = 0; rt < 4; rt++) acc[ct][rt] = (floatx4){0.f, 0.f, 0.f, 0.f};

    // One K-step: m selects the X array, h selects the 32-elem half of the
    // 64-elem D dim. k' (Wt k-index) = (m*2+h)*32 + quad*8. All indices static.
#define KSTEP(XP, m, h)                                                          \
    {                                                                            \
        const unsigned short* xa = (XP) + rowbase * DD + (h) * 32 + quad * 8;    \
        half8_t a0 = *(const half8_t*)(xa + (0 * 16 + col) * DD);                \
        half8_t a1 = *(const half8_t*)(xa + (1 * 16 + col) * DD);                \
        half8_t a2 = *(const half8_t*)(xa + (2 * 16 + col) * DD);                \
        half8_t a3 = *(const half8_t*)(xa + (3 * 16 + col) * DD);                \
        const unsigned short* wb = Wt + ((m) * 2 + (h)) * 32 + quad * 8;         \
        half8_t b0 = *(const half8_t*)(wb + (0 * 16 + col) * KK);                \
        half8_t b1 = *(const half8_t*)(wb + (1 * 16 + col) * KK);                \
        half8_t b2 = *(const half8_t*)(wb + (2 * 16 + col) * KK);                \
        half8_t b3 = *(const half8_t*)(wb + (3 * 16 + col) * KK);                \
        acc[0][0] = __builtin_amdgcn_mfma_f32_16x16x32_f16(a0, b0, acc[0][0], 0, 0, 0); \
        acc[0][1] = __builtin_amdgcn_mfma_f32_16x16x32_f16(a1, b0, acc[0][1], 0, 0, 0); \
        acc[0][2] = __builtin_amdgcn_mfma_f32_16x16x32_f16(a2, b0, acc[0][2], 0, 0, 0); \
        acc[0][3] = __builtin_amdgcn_mfma_f32_16x16x32_f16(a3, b0, acc[0][3], 0, 0, 0); \
        acc[1][0] = __builtin_amdgcn_mfma_f32_16x16x32_f16(a0, b1, acc[1][0], 0, 0, 0); \
        acc[1][1] = __builtin_amdgcn_mfma_f32_16x16x32_f16(a1, b1, acc[1][1], 0, 0, 0); \
        acc[1][2] = __builtin_amdgcn_mfma_f32_16x16x32_f16(a2, b1, acc[1][2], 0, 0, 0); \
        acc[1][3] = __builtin_amdgcn_mfma_f32_16x16x32_f16(a3, b1, acc[1][3], 0, 0, 0); \
        acc[2][0] = __builtin_amdgcn_mfma_f32_16x16x32_f16(a0, b2, acc[2][0], 0, 0, 0); \
        acc[2][1] = __builtin_amdgcn_mfma_f32_16x16x32_f16(a1, b2, acc[2][1], 0, 0, 0); \
        acc[2][2] = __builtin_amdgcn_mfma_f32_16x16x32_f16(a2, b2, acc[2][2], 0, 0, 0); \
        acc[2][3] = __builtin_amdgcn_mfma_f32_16x16x32_f16(a3, b2, acc[2][3], 0, 0, 0); \
        acc[3][0] = __builtin_amdgcn_mfma_f32_16x16x32_f16(a0, b3, acc[3][0], 0, 0, 0); \
        acc[3][1] = __builtin_amdgcn_mfma_f32_16x16x32_f16(a1, b3, acc[3][1], 0, 0, 0); \
        acc[3][2] = __builtin_amdgcn_mfma_f32_16x16x32_f16(a2, b3, acc[3][2], 0, 0, 0); \
        acc[3][3] = __builtin_amdgcn_mfma_f32_16x16x32_f16(a3, b3, acc[3][3], 0, 0, 0); \
    }

    KSTEP(X0, 0, 0)
    KSTEP(X0, 0, 1)
    KSTEP(X1, 1, 0)
    KSTEP(X1, 1, 1)
    KSTEP(X2, 2, 0)
    KSTEP(X2, 2, 1)
    KSTEP(X3, 3, 0)
    KSTEP(X3, 3, 1)
    KSTEP(X4, 4, 0)
    KSTEP(X4, 4, 1)
#undef KSTEP

#pragma unroll
    for (int ct = 0; ct < 4; ct++) {
        int o = ct * 16 + col;
        float bv = bias[o];
#pragma unroll
        for (int rt = 0; rt < 4; rt++) {
            size_t rb = rowbase + rt * 16 + quad * 4;
#pragma unroll
            for (int r = 0; r < 4; r++) {
                out[(rb + r) * OO + o] = acc[ct][rt][r] + bv;
            }
        }
    }
}

// ---------------------------------------------------------------- launch
extern "C" void kernel_launch(void* const* d_in, const int* in_sizes, int n_in,
                              void* d_out, int out_size, void* d_ws, size_t ws_size,
                              hipStream_t stream)
{
    (void)in_sizes; (void)n_in; (void)out_size; (void)ws_size;
    const float* inputs  = (const float*)d_in[0];
    const float* adj     = (const float*)d_in[1];
    const int*   rows    = (const int*)d_in[2];
    const int*   cols    = (const int*)d_in[3];
    const float* weights = (const float*)d_in[4];
    const float* bias    = (const float*)d_in[5];
    float* out = (float*)d_out;

    char* ws = (char*)d_ws;
    size_t off = 0;
    auto alloc = [&](size_t bytes) -> char* {
        char* p = ws + off;
        off = (off + bytes + 255) & ~(size_t)255;
        return p;
    };
    float* drow    = (float*)alloc(NN * 4);
    float* dcol    = (float*)alloc(NN * 4);
    int* cnt_col   = (int*)alloc(NN * 4);
    int* cnt_row   = (int*)alloc(NN * 4);
    int* off_col   = (int*)alloc((NN + 1) * 4);
    int* off_row   = (int*)alloc((NN + 1) * 4);
    int* cur_col   = (int*)alloc(NN * 4);
    int* cur_row   = (int*)alloc(NN * 4);
    int* perm_col  = (int*)alloc(NN * 4);
    int* perm_row  = (int*)alloc(NN * 4);
    int2* edge1    = (int2*)alloc((size_t)EE * 8);
    int2* edge2    = (int2*)alloc((size_t)EE * 8);
    unsigned short* Wt = (unsigned short*)alloc((size_t)OO * KK * 2);
    unsigned short* X[MM];
    for (int m = 0; m < MM; m++) X[m] = (unsigned short*)alloc((size_t)NN * BB * DD * 2);

    // zero the atomic accumulators (drow,dcol,cnt_col,cnt_row are contiguous)
    hipMemsetAsync(drow, 0, (size_t)NN * 4 * 4, stream);

    hist_kernel<<<EE / 256, 256, 0, stream>>>(adj, rows, cols, drow, dcol,
                                              cnt_row, cnt_col);
    scan_kernel<<<2, 1024, 0, stream>>>(cnt_col, cnt_row, off_col, off_row,
                                        cur_col, cur_row);
    degsort_kernel<<<2, 1024, 0, stream>>>(off_col, off_row, perm_col, perm_row);
    scatter_kernel<<<EE / 256, 256, 0, stream>>>(adj, rows, cols, drow, dcol,
                                                 cur_col, cur_row, edge1, edge2);
    cast_kernel<<<(BB * NN * DD) / (256 * 8), 256, 0, stream>>>(inputs, X[0]);
    wprep_kernel<<<(OO * KK + 255) / 256, 256, 0, stream>>>(weights, Wt);

    const int SPMM_GRID = 512 * BB;   // 512 node-tiles x 32 b, XCD-swizzled

    // xs1 = S1 x0
    spmm_kernel<<<SPMM_GRID, 256, 0, stream>>>(X[0], nullptr, X[1], off_col,
                                               perm_col, edge1, 1.f, 0.f, 0);
    // xs2 = 2*S1 xs1 - x0
    spmm_kernel<<<SPMM_GRID, 256, 0, stream>>>(X[1], X[0], X[2], off_col,
                                               perm_col, edge1, 2.f, -1.f, 1);
    // xs3 = S2 xs1   (x0 deliberately NOT reset between supports)
    spmm_kernel<<<SPMM_GRID, 256, 0, stream>>>(X[1], nullptr, X[3], off_row,
                                               perm_row, edge2, 1.f, 0.f, 0);
    // xs4 = 2*S2 xs3 - xs1
    spmm_kernel<<<SPMM_GRID, 256, 0, stream>>>(X[3], X[1], X[4], off_row,
                                               perm_row, edge2, 2.f, -1.f, 1);

    final_mfma<<<BB * (NN / 256), 256, 0, stream>>>(X[0], X[1], X[2], X[3], X[4],
                                                    Wt, bias, out);
}

// Round 5
// 1020.521 us; speedup vs baseline: 1.4635x; 1.0044x over previous
//
#include <hip/hip_runtime.h>
#include <stdint.h>

// Problem constants (fixed by the reference).
#define NN 16384      // nodes
#define EE 524288     // edges
#define BB 32         // batch
#define DD 64         // input dim
#define OO 64         // output dim
#define MM 5          // num diffusion matrices
#define KK 320        // D*M  (GEMM reduction dim)

#define HIST_BLKS  (EE / 256)                 // 2048
#define CAST_BLKS  ((BB * NN * DD) / (256 * 8)) // 16384
#define WPREP_BLKS ((OO * KK + 255) / 256)    // 80
#define SPMM_GRID  (512 * BB)                 // 16384

typedef __attribute__((ext_vector_type(2))) _Float16 half2_t;
typedef __attribute__((ext_vector_type(8))) _Float16 half8_t;
typedef __attribute__((ext_vector_type(4))) float floatx4;

// ---------------------------------------------------------------- fused pre
// hist (atomic degree+count) + cast (fp32->fp16 x0) + wprep (W transpose),
// all independent -> one dispatch, fewer launch gaps, mixed-bottleneck overlap.
__global__ __launch_bounds__(256) void fused_pre(
    const float* __restrict__ inp, unsigned short* __restrict__ x0,
    const float* __restrict__ adj, const int* __restrict__ rows,
    const int* __restrict__ cols,
    float* __restrict__ drow, float* __restrict__ dcol,
    int* __restrict__ cnt_row, int* __restrict__ cnt_col,
    const float* __restrict__ W, unsigned short* __restrict__ Wt)
{
    unsigned int blk = blockIdx.x;
    int t = threadIdx.x;
    if (blk < HIST_BLKS) {
        int e = blk * 256 + t;
        float a = adj[e];
        int r = rows[e], c = cols[e];
        atomicAdd(&drow[r], a);
        atomicAdd(&dcol[c], a);
        atomicAdd(&cnt_row[r], 1);
        atomicAdd(&cnt_col[c], 1);
    } else if (blk < HIST_BLKS + CAST_BLKS) {
        size_t i = ((size_t)(blk - HIST_BLKS) * 256 + t) * 8;
        float4 a = *(const float4*)(inp + i);
        float4 b = *(const float4*)(inp + i + 4);
        half2_t h0 = {(_Float16)a.x, (_Float16)a.y};
        half2_t h1 = {(_Float16)a.z, (_Float16)a.w};
        half2_t h2 = {(_Float16)b.x, (_Float16)b.y};
        half2_t h3 = {(_Float16)b.z, (_Float16)b.w};
        uint4 o;
        o.x = __builtin_bit_cast(unsigned int, h0);
        o.y = __builtin_bit_cast(unsigned int, h1);
        o.z = __builtin_bit_cast(unsigned int, h2);
        o.w = __builtin_bit_cast(unsigned int, h3);
        *(uint4*)(x0 + i) = o;
    } else {
        int i = (blk - HIST_BLKS - CAST_BLKS) * 256 + t;
        if (i < OO * KK) {
            int o = i / KK;
            int kp = i - o * KK;
            int m = kp >> 6;
            int d = kp & 63;
            _Float16 h = (_Float16)W[(d * MM + m) * OO + o];
            Wt[i] = __builtin_bit_cast(unsigned short, h);
        }
    }
}

// ---------------------------------------------------------------- scan
// One block per array (grid=2), 1024 threads, 16 elements/thread.
__global__ __launch_bounds__(1024) void scan_kernel(
    const int* __restrict__ cnt_col, const int* __restrict__ cnt_row,
    int* __restrict__ off_col, int* __restrict__ off_row,
    int* __restrict__ cur_col, int* __restrict__ cur_row)
{
    const int* cnt = (blockIdx.x == 0) ? cnt_col : cnt_row;
    int* off = (blockIdx.x == 0) ? off_col : off_row;
    int* cur = (blockIdx.x == 0) ? cur_col : cur_row;

    __shared__ int part[1024];
    int t = threadIdx.x;
    int base = t * 16;
    int local[16];
    int s = 0;
#pragma unroll
    for (int i = 0; i < 16; i++) { local[i] = cnt[base + i]; s += local[i]; }
    part[t] = s;
    __syncthreads();
    for (int d = 1; d < 1024; d <<= 1) {
        int v = (t >= d) ? part[t - d] : 0;
        __syncthreads();
        part[t] += v;
        __syncthreads();
    }
    int run = (t == 0) ? 0 : part[t - 1];
#pragma unroll
    for (int i = 0; i < 16; i++) {
        off[base + i] = run;
        cur[base + i] = run;
        run += local[i];
    }
    if (t == 1023) off[NN] = run;
}

// ---------------------------------------------------------------- fused build
// blocks 0..1: degree counting-sort perm (as before); blocks 2..: scatter
// (CSR edge build). Both depend only on scan output -> one dispatch.
__global__ __launch_bounds__(1024) void fused_build(
    const int* __restrict__ off_col, const int* __restrict__ off_row,
    int* __restrict__ perm_col, int* __restrict__ perm_row,
    const float* __restrict__ adj, const int* __restrict__ rows,
    const int* __restrict__ cols,
    const float* __restrict__ drow, const float* __restrict__ dcol,
    int* __restrict__ cur_col, int* __restrict__ cur_row,
    int2* __restrict__ edge1, int2* __restrict__ edge2)
{
    unsigned int blk = blockIdx.x;
    int t = threadIdx.x;
    if (blk < 2) {
        const int* off = (blk == 0) ? off_col : off_row;
        int* perm = (blk == 0) ? perm_col : perm_row;
        __shared__ int bins[512];
        __shared__ int cur[512];
        if (t < 512) bins[t] = 0;
        __syncthreads();
        for (int i = t; i < NN; i += 1024) {
            int d = off[i + 1] - off[i];
            if (d > 511) d = 511;
            atomicAdd(&bins[d], 1);
        }
        __syncthreads();
        for (int sh = 1; sh < 512; sh <<= 1) {
            int v = (t < 512 && t >= sh) ? bins[t - sh] : 0;
            __syncthreads();
            if (t < 512) bins[t] += v;
            __syncthreads();
        }
        if (t < 512) cur[t] = (t == 0) ? 0 : bins[t - 1];
        __syncthreads();
        for (int i = t; i < NN; i += 1024) {
            int d = off[i + 1] - off[i];
            if (d > 511) d = 511;
            int p = atomicAdd(&cur[d], 1);
            perm[p] = i;
        }
    } else {
        int e = (blk - 2) * 1024 + t;
        if (e < EE) {
            float a = adj[e];
            int r = rows[e], c = cols[e];
            float dr = drow[r];
            float idr = (dr > 0.f) ? (1.f / dr) : 0.f;
            float dc = dcol[c];
            float idc = (dc > 0.f) ? (1.f / dc) : 0.f;
            _Float16 h1 = (_Float16)(a * idr);
            _Float16 h2 = (_Float16)(a * idc);
            unsigned short u1 = __builtin_bit_cast(unsigned short, h1);
            unsigned short u2 = __builtin_bit_cast(unsigned short, h2);
            int p1 = atomicAdd(&cur_col[c], 1);   // support1: dst=cols, src=rows
            edge1[p1] = make_int2(r, (int)(u1 | ((unsigned int)u1 << 16)));
            int p2 = atomicAdd(&cur_row[r], 1);   // support2: dst=rows, src=cols
            edge2[p2] = make_int2(c, (int)(u2 | ((unsigned int)u2 << 16)));
        }
    }
}

// ---------------------------------------------------------------- spmm
// One block = 32 dst nodes x ONE batch slice b. Thread t: node =
// perm[ntile*32+(t>>3)] (degree-sorted), d-group = (t&7)*8.
// XCD swizzle: blkid&7 selects XCD; b = bhi*8 + xcd so all concurrent blocks
// on an XCD share one 2 MB X b-slice (captured in that XCD's 4 MB L2).
// 8-deep gather pipeline; next-8 edge tuples prefetched branchlessly.
template<int HAS_Z>
__device__ __forceinline__ void spmm_body(
    unsigned int l,
    const unsigned short* __restrict__ xin,
    const unsigned short* __restrict__ z,
    unsigned short* __restrict__ xout,
    const int* __restrict__ off, const int* __restrict__ perm,
    const int2* __restrict__ edges,
    float alpha, float beta)
{
    int xcd  = l & 7;
    unsigned int s = l >> 3;              // 0..2047
    int bhi  = s >> 9;                    // 0..3
    int ntile = s & 511;                  // 0..511
    int b = bhi * 8 + xcd;

    int t = threadIdx.x;
    int n = perm[ntile * 32 + (t >> 3)];
    unsigned int dgb = (unsigned int)(t & 7) * 16u;   // byte offset of d-group
    int e0 = off[n], e1 = off[n + 1];
    const char* xbB = (const char*)(xin + (size_t)b * NN * DD);

    half2_t acc0 = (half2_t)0, acc1 = (half2_t)0, acc2 = (half2_t)0, acc3 = (half2_t)0;

#define GATHER(ED) (*(const uint4*)(xbB + (((unsigned int)(ED).x) << 7) + dgb))
#define FMA4(V, W2)                                                       \
    do {                                                                  \
        acc0 = __builtin_bit_cast(half2_t, (V).x) * (W2) + acc0;          \
        acc1 = __builtin_bit_cast(half2_t, (V).y) * (W2) + acc1;          \
        acc2 = __builtin_bit_cast(half2_t, (V).z) * (W2) + acc2;          \
        acc3 = __builtin_bit_cast(half2_t, (V).w) * (W2) + acc3;          \
    } while (0)

    int ecnt = e1 - e0;
    int nb8 = ecnt >> 3;          // number of full groups of 8 edges

    int2 ed0, ed1, ed2, ed3, ed4, ed5, ed6, ed7;
    if (nb8 > 0) {
        ed0 = edges[e0];     ed1 = edges[e0 + 1];
        ed2 = edges[e0 + 2]; ed3 = edges[e0 + 3];
        ed4 = edges[e0 + 4]; ed5 = edges[e0 + 5];
        ed6 = edges[e0 + 6]; ed7 = edges[e0 + 7];
    }
    for (int it = 0; it < nb8; ++it) {
        uint4 v0 = GATHER(ed0);
        uint4 v1 = GATHER(ed1);
        uint4 v2 = GATHER(ed2);
        uint4 v3 = GATHER(ed3);
        uint4 v4 = GATHER(ed4);
        uint4 v5 = GATHER(ed5);
        uint4 v6 = GATHER(ed6);
        uint4 v7 = GATHER(ed7);
        half2_t w0 = __builtin_bit_cast(half2_t, ed0.y);
        half2_t w1 = __builtin_bit_cast(half2_t, ed1.y);
        half2_t w2 = __builtin_bit_cast(half2_t, ed2.y);
        half2_t w3 = __builtin_bit_cast(half2_t, ed3.y);
        half2_t w4 = __builtin_bit_cast(half2_t, ed4.y);
        half2_t w5 = __builtin_bit_cast(half2_t, ed5.y);
        half2_t w6 = __builtin_bit_cast(half2_t, ed6.y);
        half2_t w7 = __builtin_bit_cast(half2_t, ed7.y);

        int ep = (it + 1 < nb8) ? (e0 + (it + 1) * 8) : e0;
        int2 nd0 = edges[ep];     int2 nd1 = edges[ep + 1];
        int2 nd2 = edges[ep + 2]; int2 nd3 = edges[ep + 3];
        int2 nd4 = edges[ep + 4]; int2 nd5 = edges[ep + 5];
        int2 nd6 = edges[ep + 6]; int2 nd7 = edges[ep + 7];

        FMA4(v0, w0);
        FMA4(v1, w1);
        FMA4(v2, w2);
        FMA4(v3, w3);
        FMA4(v4, w4);
        FMA4(v5, w5);
        FMA4(v6, w6);
        FMA4(v7, w7);

        ed0 = nd0; ed1 = nd1; ed2 = nd2; ed3 = nd3;
        ed4 = nd4; ed5 = nd5; ed6 = nd6; ed7 = nd7;
    }
    for (int e = e0 + nb8 * 8; e < e1; ++e) {
        int2 ed = edges[e];
        half2_t wv = __builtin_bit_cast(half2_t, ed.y);
        uint4 v = GATHER(ed);
        FMA4(v, wv);
    }
#undef FMA4
#undef GATHER

    size_t fo = ((size_t)b * NN + n) * DD + (dgb >> 1);
    if (HAS_Z) {
        uint4 zv = *(const uint4*)(z + fo);
        half2_t al = {(_Float16)alpha, (_Float16)alpha};
        half2_t be = {(_Float16)beta, (_Float16)beta};
        acc0 = al * acc0 + be * __builtin_bit_cast(half2_t, zv.x);
        acc1 = al * acc1 + be * __builtin_bit_cast(half2_t, zv.y);
        acc2 = al * acc2 + be * __builtin_bit_cast(half2_t, zv.z);
        acc3 = al * acc3 + be * __builtin_bit_cast(half2_t, zv.w);
    }

    uint4 o;
    o.x = __builtin_bit_cast(unsigned int, acc0);
    o.y = __builtin_bit_cast(unsigned int, acc1);
    o.z = __builtin_bit_cast(unsigned int, acc2);
    o.w = __builtin_bit_cast(unsigned int, acc3);
    *(uint4*)(xout + fo) = o;
}

template<int HAS_Z>
__global__ __launch_bounds__(256) void spmm_kernel(
    const unsigned short* __restrict__ xin,
    const unsigned short* __restrict__ z,
    unsigned short* __restrict__ xout,
    const int* __restrict__ off, const int* __restrict__ perm,
    const int2* __restrict__ edges,
    float alpha, float beta)
{
    spmm_body<HAS_Z>(blockIdx.x, xin, z, xout, off, perm, edges, alpha, beta);
}

// Merged middle dispatches: X2 = 2*S1*X1 - X0  and  X3 = S2*X1.
// Both depend only on X1 -> one double-grid dispatch (tail overlap, one less
// launch boundary).
__global__ __launch_bounds__(256) void spmm_dual(
    const unsigned short* __restrict__ X0, const unsigned short* __restrict__ X1,
    unsigned short* __restrict__ X2, unsigned short* __restrict__ X3,
    const int* __restrict__ off_col, const int* __restrict__ perm_col,
    const int2* __restrict__ edge1,
    const int* __restrict__ off_row, const int* __restrict__ perm_row,
    const int2* __restrict__ edge2)
{
    unsigned int blk = blockIdx.x;
    if (blk < SPMM_GRID) {
        spmm_body<1>(blk, X1, X0, X2, off_col, perm_col, edge1, 2.f, -1.f);
    } else {
        spmm_body<0>(blk - SPMM_GRID, X1, nullptr, X3, off_row, perm_row, edge2, 1.f, 0.f);
    }
}

// ---------------------------------------------------------------- final GEMM (MFMA)
// No-LDS streaming version, occupancy-tuned: wave owns 32 rows (2 row-tiles),
// acc[4 ct][2 rt] = 32 VGPR -> total ~75-90 VGPR, __launch_bounds__(256,5)
// gives 5 waves/SIMD (62.5% occupancy) vs 35% before -> hides the direct
// HBM A-fragment load latency. Extra B loads are L1-hot Wt (40 KB).
// Block = 128 rows (4 waves), grid = BB * NN/128 = 4096.
__global__ __launch_bounds__(256, 5) void final_mfma(
    const unsigned short* __restrict__ X0, const unsigned short* __restrict__ X1,
    const unsigned short* __restrict__ X2, const unsigned short* __restrict__ X3,
    const unsigned short* __restrict__ X4,
    const unsigned short* __restrict__ Wt, const float* __restrict__ bias,
    float* __restrict__ out)
{
    int blk = blockIdx.x;              // 0..4095
    int b = blk >> 7;                  // 0..31
    int n0 = (blk & 127) * 128;        // 0..16256
    int t = threadIdx.x;
    int wave = t >> 6;
    int lane = t & 63;
    int col = lane & 15;
    int quad = lane >> 4;

    size_t rowbase = (size_t)b * NN + n0 + wave * 32;   // this wave's 32 rows

    floatx4 acc[4][2];                 // [ct][rt]
#pragma unroll
    for (int ct = 0; ct < 4; ct++)
#pragma unroll
        for (int rt = 0; rt < 2; rt++) acc[ct][rt] = (floatx4){0.f, 0.f, 0.f, 0.f};

    // One K-step: m selects the X array, h selects the 32-elem half of the
    // 64-elem D dim. k' (Wt k-index) = (m*2+h)*32 + quad*8. All indices static.
#define KSTEP(XP, m, h)                                                          \
    {                                                                            \
        const unsigned short* xa = (XP) + rowbase * DD + (h) * 32 + quad * 8;    \
        half8_t a0 = *(const half8_t*)(xa + (0 * 16 + col) * DD);                \
        half8_t a1 = *(const half8_t*)(xa + (1 * 16 + col) * DD);                \
        const unsigned short* wb = Wt + ((m) * 2 + (h)) * 32 + quad * 8;         \
        half8_t b0 = *(const half8_t*)(wb + (0 * 16 + col) * KK);                \
        half8_t b1 = *(const half8_t*)(wb + (1 * 16 + col) * KK);                \
        half8_t b2 = *(const half8_t*)(wb + (2 * 16 + col) * KK);                \
        half8_t b3 = *(const half8_t*)(wb + (3 * 16 + col) * KK);                \
        acc[0][0] = __builtin_amdgcn_mfma_f32_16x16x32_f16(a0, b0, acc[0][0], 0, 0, 0); \
        acc[0][1] = __builtin_amdgcn_mfma_f32_16x16x32_f16(a1, b0, acc[0][1], 0, 0, 0); \
        acc[1][0] = __builtin_amdgcn_mfma_f32_16x16x32_f16(a0, b1, acc[1][0], 0, 0, 0); \
        acc[1][1] = __builtin_amdgcn_mfma_f32_16x16x32_f16(a1, b1, acc[1][1], 0, 0, 0); \
        acc[2][0] = __builtin_amdgcn_mfma_f32_16x16x32_f16(a0, b2, acc[2][0], 0, 0, 0); \
        acc[2][1] = __builtin_amdgcn_mfma_f32_16x16x32_f16(a1, b2, acc[2][1], 0, 0, 0); \
        acc[3][0] = __builtin_amdgcn_mfma_f32_16x16x32_f16(a0, b3, acc[3][0], 0, 0, 0); \
        acc[3][1] = __builtin_amdgcn_mfma_f32_16x16x32_f16(a1, b3, acc[3][1], 0, 0, 0); \
    }

    KSTEP(X0, 0, 0)
    KSTEP(X0, 0, 1)
    KSTEP(X1, 1, 0)
    KSTEP(X1, 1, 1)
    KSTEP(X2, 2, 0)
    KSTEP(X2, 2, 1)
    KSTEP(X3, 3, 0)
    KSTEP(X3, 3, 1)
    KSTEP(X4, 4, 0)
    KSTEP(X4, 4, 1)
#undef KSTEP

#pragma unroll
    for (int ct = 0; ct < 4; ct++) {
        int o = ct * 16 + col;
        float bv = bias[o];
#pragma unroll
        for (int rt = 0; rt < 2; rt++) {
            size_t rb = rowbase + rt * 16 + quad * 4;
#pragma unroll
            for (int r = 0; r < 4; r++) {
                out[(rb + r) * OO + o] = acc[ct][rt][r] + bv;
            }
        }
    }
}

// ---------------------------------------------------------------- launch
extern "C" void kernel_launch(void* const* d_in, const int* in_sizes, int n_in,
                              void* d_out, int out_size, void* d_ws, size_t ws_size,
                              hipStream_t stream)
{
    (void)in_sizes; (void)n_in; (void)out_size; (void)ws_size;
    const float* inputs  = (const float*)d_in[0];
    const float* adj     = (const float*)d_in[1];
    const int*   rows    = (const int*)d_in[2];
    const int*   cols    = (const int*)d_in[3];
    const float* weights = (const float*)d_in[4];
    const float* bias    = (const float*)d_in[5];
    float* out = (float*)d_out;

    char* ws = (char*)d_ws;
    size_t off = 0;
    auto alloc = [&](size_t bytes) -> char* {
        char* p = ws + off;
        off = (off + bytes + 255) & ~(size_t)255;
        return p;
    };
    float* drow    = (float*)alloc(NN * 4);
    float* dcol    = (float*)alloc(NN * 4);
    int* cnt_col   = (int*)alloc(NN * 4);
    int* cnt_row   = (int*)alloc(NN * 4);
    int* off_col   = (int*)alloc((NN + 1) * 4);
    int* off_row   = (int*)alloc((NN + 1) * 4);
    int* cur_col   = (int*)alloc(NN * 4);
    int* cur_row   = (int*)alloc(NN * 4);
    int* perm_col  = (int*)alloc(NN * 4);
    int* perm_row  = (int*)alloc(NN * 4);
    int2* edge1    = (int2*)alloc((size_t)EE * 8);
    int2* edge2    = (int2*)alloc((size_t)EE * 8);
    unsigned short* Wt = (unsigned short*)alloc((size_t)OO * KK * 2);
    unsigned short* X[MM];
    for (int m = 0; m < MM; m++) X[m] = (unsigned short*)alloc((size_t)NN * BB * DD * 2);

    // zero the atomic accumulators (drow,dcol,cnt_col,cnt_row are contiguous)
    hipMemsetAsync(drow, 0, (size_t)NN * 4 * 4, stream);

    fused_pre<<<HIST_BLKS + CAST_BLKS + WPREP_BLKS, 256, 0, stream>>>(
        inputs, X[0], adj, rows, cols, drow, dcol, cnt_row, cnt_col,
        weights, Wt);
    scan_kernel<<<2, 1024, 0, stream>>>(cnt_col, cnt_row, off_col, off_row,
                                        cur_col, cur_row);
    fused_build<<<2 + EE / 1024, 1024, 0, stream>>>(
        off_col, off_row, perm_col, perm_row,
        adj, rows, cols, drow, dcol, cur_col, cur_row, edge1, edge2);

    // xs1 = S1 x0
    spmm_kernel<0><<<SPMM_GRID, 256, 0, stream>>>(X[0], nullptr, X[1], off_col,
                                                  perm_col, edge1, 1.f, 0.f);
    // xs2 = 2*S1 xs1 - x0   AND   xs3 = S2 xs1   (independent, merged)
    spmm_dual<<<2 * SPMM_GRID, 256, 0, stream>>>(X[0], X[1], X[2], X[3],
                                                 off_col, perm_col, edge1,
                                                 off_row, perm_row, edge2);
    // xs4 = 2*S2 xs3 - xs1
    spmm_kernel<1><<<SPMM_GRID, 256, 0, stream>>>(X[3], X[1], X[4], off_row,
                                                  perm_row, edge2, 2.f, -1.f);

    final_mfma<<<BB * (NN / 128), 256, 0, stream>>>(X[0], X[1], X[2], X[3], X[4],
                                                    Wt, bias, out);
}